// Round 10
// baseline (653.622 us; speedup 1.0000x reference)
//
#include <hip/hip_runtime.h>
#include <hip/hip_bf16.h>

// CrystalGraphConvNet fused pipeline for MI355X (gfx950).
// Inputs f32 (runtime-detected from gamma; bf16 path kept).
//
// u@w1 = x@W_a + x_gathered@W_n + nf@W_f. xay = x@[W_a|W_n] (one N=1024 GEMM);
// conv v11 (kept): per phase, bfr loads issue first, then yy gathers (vmcnt
// drains in issue order -> MFMA waits only on bfr); ~88.5us structural floor.
// gemm v5 = v4 + NTILES template: 128 x (128*NTILES) output per block.
// NTILES=2 everywhere (emb/xy/h2): 32 MFMA/wave between barriers (2x work
// per DMA-drain stall), A re-fetched 4x not 8x (xy), half the blocks.
// acc[2][4][4]=128 f32/thread; staging LDS 48KB dbuf union'd with C-repack
// tile -> 3 blocks/CU (LDS-bound). v4's coalesced C-store kept (per-ct pass).
// v3's T3 dbuf kept (one barrier per K-step).
// conv v9: neighbor idx in sNF row pad -> LDS 32768 -> 5 blocks/CU.
// v6-v8 lesson: keep bf16 sZ stride-268. A-side buffers padded to 20096
// rows (branchless staging); stats/stores keep the row<M guard.

#define N_ATOM 20000
#define N_PAD  20096    // 157*128, A-side row padding for branchless staging
#define AF     256
#define F2     512
#define ORIG   92
#define ORIG_P 96
#define BB     200
#define KK     50
#define BN_EPS 1e-5f
#define ZS2    268      // sZ row stride (bf16): 256 + 12 pad -> q-groups bank-spread
#define CTS    132      // gemm C-repack tile stride (shorts)

// canonical small-tensor block (bf16) element offsets
#define OFF_B1   0        // 3*512
#define OFF_B2   1536     // 3*256
#define OFF_GAM  2304     // 3*256
#define OFF_BET  3072     // 3*256
#define OFF_EMBB 3840     // 256
#define OFF_FCB  4096     // 256
#define OFF_FCW  4352     // 260*256
#define OFF_OW   70912    // 256
#define OFF_OB   71168    // 1
#define OFF_M2   71169    // 200*4
#define N_SMALL  71969

// prep_all segment sizes
#define S_AF   (N_ATOM * ORIG_P)
#define S_EMB  (AF * ORIG_P)
#define S_W12  (3 * 1024 * 256)
#define S_W1F  (3 * 512 * 64)
#define S_W2   (3 * AF * F2)
#define S_SM   N_SMALL
#define S_TOT  (S_AF + S_EMB + S_W12 + S_W1F + S_W2 + S_SM)

using bf16x8 = __attribute__((ext_vector_type(8))) short;
using f32x4  = __attribute__((ext_vector_type(4))) float;

__device__ __forceinline__ float bf2f(__hip_bfloat16 v) { return __bfloat162float(v); }
__device__ __forceinline__ __hip_bfloat16 f2bf(float v) { return __float2bfloat16(v); }
__device__ __forceinline__ unsigned short f2bfbits(float f) {   // RNE f32->bf16 bits
    unsigned u = __float_as_uint(f);
    u += 0x7fffu + ((u >> 16) & 1u);
    return (unsigned short)(u >> 16);
}
__device__ __forceinline__ float bfbits2f(unsigned short u) {
    return __uint_as_float(((unsigned)u) << 16);
}
// pack two f32 -> u32 of two RNE bf16. Bit-identical to f2bfbits pair.
// NOTE: v_cvt_pk_bf16_f32 is NOT RNE-equivalent (tried, failed correctness).
__device__ __forceinline__ unsigned pack2bf(float lo, float hi) {
    unsigned ul = __float_as_uint(lo);
    unsigned uh = __float_as_uint(hi);
    ul += 0x7fffu + ((ul >> 16) & 1u);
    uh += 0x7fffu + ((uh >> 16) & 1u);
    return __builtin_amdgcn_perm(uh, ul, 0x07060302u);
}
__device__ __forceinline__ float softplus_f(float x) {
    return fmaxf(x, 0.f) + __logf(1.f + __expf(-fabsf(x)));
}
__device__ __forceinline__ float ld_any(const void* p, long idx, bool isf32) {
    return isf32 ? ((const float*)p)[idx] : bf2f(((const __hip_bfloat16*)p)[idx]);
}

// ---------------- dtype detect ----------------------------------------------
__global__ void detect_dtype(const unsigned* __restrict__ gamma_raw,
                             unsigned* __restrict__ flag) {
    unsigned u = gamma_raw[0];              // 1.0f = 0x3F800000 ; bf16 pair = 0x3F803F80
    flag[0] = ((u & 0xFFFFu) == 0u) ? 1u : 0u;
}

// ---------------- prep: nf -> canonical bf16 (once per launch) ---------------
__global__ __launch_bounds__(256) void prep_nf(const void* __restrict__ nf,
                                               const unsigned* __restrict__ dflag,
                                               unsigned* __restrict__ out) {
    bool isf32 = dflag[0] != 0u;
    int idx = blockIdx.x * 256 + threadIdx.x;        // one per 4 elems
    if (idx >= N_ATOM * 12 * 64 / 4) return;
    if (isf32) {
        float4 v = ((const float4*)nf)[idx];
        out[idx * 2]     = pack2bf(v.x, v.y);
        out[idx * 2 + 1] = pack2bf(v.z, v.w);
    } else {
        ((uint2*)out)[idx] = ((const uint2*)nf)[idx];
    }
}

// ---------------- merged prep ------------------------------------------------
__global__ __launch_bounds__(256)
void prep_all(const void* af, const void* emb_w, const void* w1, const void* w2,
              const void* b1, const void* b2, const void* gam, const void* bet,
              const void* embb, const void* fcb, const void* fcw,
              const void* ow, const void* ob, const void* m2,
              const unsigned* __restrict__ dflag,
              __hip_bfloat16* __restrict__ af_pad, __hip_bfloat16* __restrict__ embT,
              __hip_bfloat16* __restrict__ w1T2, __hip_bfloat16* __restrict__ w1Tf,
              __hip_bfloat16* __restrict__ w2T, __hip_bfloat16* __restrict__ smalls) {
    bool isf32 = dflag[0] != 0u;
    int i = blockIdx.x * 256 + threadIdx.x;
    if (i < S_AF) {
        int r = i / ORIG_P, k = i - r * ORIG_P;
        af_pad[i] = (k < ORIG) ? f2bf(ld_any(af, (long)r * ORIG + k, isf32)) : f2bf(0.f);
        return;
    }
    i -= S_AF;
    if (i < S_EMB) {
        int n = i / ORIG_P, k = i - n * ORIG_P;
        embT[i] = (k < ORIG) ? f2bf(ld_any(emb_w, (long)k * AF + n, isf32)) : f2bf(0.f);
        return;
    }
    i -= S_EMB;
    if (i < S_W12) {
        int l = i / (1024 * 256); int rem = i - l * (1024 * 256);
        int c = rem / 256, k = rem - c * 256;
        long src = (c < 512) ? ((long)(l * 576 + k) * F2 + c)
                             : ((long)(l * 576 + 256 + k) * F2 + (c - 512));
        w1T2[i] = f2bf(ld_any(w1, src, isf32));
        return;
    }
    i -= S_W12;
    if (i < S_W1F) {
        int l = i / (512 * 64); int rem = i - l * (512 * 64);
        int c = rem / 64, k = rem - c * 64;
        w1Tf[i] = f2bf(ld_any(w1, (long)(l * 576 + 512 + k) * F2 + c, isf32));
        return;
    }
    i -= S_W1F;
    if (i < S_W2) {
        int l = i / (AF * F2); int rem = i - l * (AF * F2);
        int n = rem / F2, k = rem - n * F2;
        w2T[i] = f2bf(ld_any(w2, (long)(l * F2 + k) * AF + n, isf32));
        return;
    }
    i -= S_W2;
    if (i >= S_SM) return;
    float v;
    if      (i < OFF_B2)   v = ld_any(b1,   i - OFF_B1,  isf32);
    else if (i < OFF_GAM)  v = ld_any(b2,   i - OFF_B2,  isf32);
    else if (i < OFF_BET)  v = ld_any(gam,  i - OFF_GAM, isf32);
    else if (i < OFF_EMBB) v = ld_any(bet,  i - OFF_BET, isf32);
    else if (i < OFF_FCB)  v = ld_any(embb, i - OFF_EMBB,isf32);
    else if (i < OFF_OW)   v = (i < OFF_FCW) ? ld_any(fcb, i - OFF_FCB, isf32)
                                             : ld_any(fcw, i - OFF_FCW, isf32);
    else if (i < OFF_OB)   v = ld_any(ow,   i - OFF_OW,  isf32);
    else if (i < OFF_M2)   v = ld_any(ob,   i - OFF_OB,  isf32);
    else                   v = ld_any(m2,   i - OFF_M2,  isf32);
    smalls[i] = f2bf(v);
}

// ---------------- generic MFMA GEMM: C = act(A @ B + bias) -------------------
// Output tile 128 x (128*NTILES) per block. T3 dbuf (one barrier/K-step) +
// per-ct LDS-repack coalesced C-store. sMem union: staging (2 bufs x
// (A 4096 + B 4096*NTILES) shorts) vs C-repack (128*CTS shorts).
// A must have >= ceil(M/128)*128 readable rows; stats/stores guard row<M.
template <bool OUT_BF16, int NTILES>
__global__ __launch_bounds__(256)
void gemm_kernel(const __hip_bfloat16* __restrict__ A, int lda,
                 const __hip_bfloat16* __restrict__ BT, int ldb,
                 void* __restrict__ Cp, int M, int ldc, int K,
                 const __hip_bfloat16* __restrict__ bias, int act,
                 float* __restrict__ st) {
    constexpr int BUFS = 4096 * (1 + NTILES);          // shorts per dbuf slot
    constexpr int SMEMN = (2 * BUFS > 128 * CTS) ? 2 * BUFS : 128 * CTS;
    __shared__ __align__(16) unsigned short sMem[SMEMN];
    __shared__ float sS[128 * NTILES], sS2[128 * NTILES];
    int tid  = threadIdx.x;
    int mt   = blockIdx.x, nt = blockIdx.y;
    int wave = tid >> 6, lane = tid & 63, q = lane >> 4, ln = lane & 15;
    int wr   = wave >> 1, wc = wave & 1;

    if (st) for (int i = tid; i < 128 * NTILES; i += 256) { sS[i] = 0.f; sS2[i] = 0.f; }

    const __hip_bfloat16* Abase = A + (size_t)mt * 128 * lda;
    const __hip_bfloat16* Bbase = BT + (size_t)nt * (128 * NTILES) * ldb;

    auto stage = [&](int buf, int k0) {
        const __hip_bfloat16* Ab = Abase + k0;
        const __hip_bfloat16* Bb = Bbase + k0;
        unsigned short* sAb = sMem + buf * BUFS;
        unsigned short* sBb = sAb + 4096;
#pragma unroll
        for (int jj = 0; jj < 2; jj++) {
            int idx = jj * 256 + tid;
            int r = idx >> 2, c = (idx & 3) * 8;
            __builtin_amdgcn_global_load_lds(
                (const __attribute__((address_space(1))) void*)(Ab + (size_t)r * lda + c),
                (__attribute__((address_space(3))) void*)(sAb + (jj * 256 + wave * 64) * 8),
                16, 0, 0);
        }
#pragma unroll
        for (int jj = 0; jj < 2 * NTILES; jj++) {
            int idx = jj * 256 + tid;
            int r = idx >> 2, c = (idx & 3) * 8;
            __builtin_amdgcn_global_load_lds(
                (const __attribute__((address_space(1))) void*)(Bb + (size_t)r * ldb + c),
                (__attribute__((address_space(3))) void*)(sBb + (jj * 256 + wave * 64) * 8),
                16, 0, 0);
        }
    };

    f32x4 acc[NTILES][4][4];
#pragma unroll
    for (int ct = 0; ct < NTILES; ct++)
        for (int i = 0; i < 4; i++)
            for (int j = 0; j < 4; j++) acc[ct][i][j] = (f32x4){0.f, 0.f, 0.f, 0.f};

    stage(0, 0);
    __syncthreads();                       // drains tile-0 DMA, syncs all waves
    int cur = 0;
    for (int k0 = 0; k0 < K; k0 += 32) {
        if (k0 + 32 < K) stage(cur ^ 1, k0 + 32);      // next tile in flight
        const unsigned short* sAc = sMem + cur * BUFS;
        const unsigned short* sBc = sAc + 4096;
        bf16x8 af[4];
#pragma unroll
        for (int i = 0; i < 4; i++)
            af[i] = *(const bf16x8*)(&sAc[(wr * 64 + i * 16 + ln) * 32 + q * 8]);
#pragma unroll
        for (int ct = 0; ct < NTILES; ct++) {
            bf16x8 bf[4];
#pragma unroll
            for (int j = 0; j < 4; j++)
                bf[j] = *(const bf16x8*)(&sBc[(ct * 128 + wc * 64 + j * 16 + ln) * 32 + q * 8]);
#pragma unroll
            for (int i = 0; i < 4; i++)
#pragma unroll
                for (int j = 0; j < 4; j++)
                    acc[ct][i][j] = __builtin_amdgcn_mfma_f32_16x16x32_bf16(af[i], bf[j], acc[ct][i][j], 0, 0, 0);
        }
        __syncthreads();                   // drains next-tile DMA + readers done
        cur ^= 1;
    }

    if constexpr (OUT_BF16) {
#pragma unroll
        for (int ct = 0; ct < NTILES; ct++) {
            if (ct) __syncthreads();       // prev store pass LDS reads done
            // phase 1: values -> sMem C-tile [128][CTS]
            for (int j = 0; j < 4; j++) {
                int cl  = wc * 64 + j * 16 + ln;
                int col = nt * (128 * NTILES) + ct * 128 + cl;
                float bv = bias ? bf2f(bias[col]) : 0.f;
                float ls = 0.f, ls2 = 0.f;
                for (int i = 0; i < 4; i++) {
                    for (int r = 0; r < 4; r++) {
                        int rl = wr * 64 + i * 16 + q * 4 + r;
                        float v = acc[ct][i][j][r] + bv;
                        if (st && mt * 128 + rl < M) { ls += v; ls2 += v * v; }
                        if (act == 1) v = softplus_f(v);
                        sMem[rl * CTS + cl] = f2bfbits(v);
                    }
                }
                if (st) { atomicAdd(&sS[ct * 128 + cl], ls); atomicAdd(&sS2[ct * 128 + cl], ls2); }
            }
            __syncthreads();
            // phase 2: coalesced stores — 16 lanes = one 256B row run.
#pragma unroll
            for (int it = 0; it < 8; it++) {
                int fi = it * 256 + tid;
                int rl = fi >> 4, c8 = (fi & 15) * 8;
                int row = mt * 128 + rl;
                if (row < M) {
                    uint4 v = *(const uint4*)(&sMem[rl * CTS + c8]);
                    *(uint4*)((__hip_bfloat16*)Cp + (size_t)row * ldc +
                              nt * (128 * NTILES) + ct * 128 + c8) = v;
                }
            }
        }
        if (st) {
            for (int i = tid; i < 128 * NTILES; i += 256) {
                int col = nt * (128 * NTILES) + i;
                atomicAdd(&st[col], sS[i]);
                atomicAdd(&st[AF + col], sS2[i]);
            }
        }
    } else {
        for (int ct = 0; ct < NTILES; ct++) {
            for (int j = 0; j < 4; j++) {
                int cl  = wc * 64 + j * 16 + ln;
                int col = nt * (128 * NTILES) + ct * 128 + cl;
                float bv = bias ? bf2f(bias[col]) : 0.f;
                for (int i = 0; i < 4; i++) {
                    for (int r = 0; r < 4; r++) {
                        int row = mt * 128 + wr * 64 + i * 16 + q * 4 + r;
                        if (row >= M) continue;
                        float v = acc[ct][i][j][r] + bv;
                        if (act == 1) v = softplus_f(v);
                        ((float*)Cp)[(size_t)row * ldc + col] = v;
                    }
                }
            }
        }
    }
}

// ---------------- fused conv v11 --------------------------------------------
// 4 atoms/block, 5000 blocks. Per phase (256 cols): issue bfr (both halves)
// FIRST, then yy/xau/b1u gathers -> MFMA (waits only on bfr, gathers stay in
// flight) -> z to LDS -> barrier -> epilogue consumes gather regs.
// Neighbor idx lives in sNF's per-row pad (elem 64) -> LDS fits 5 blocks/CU.
__global__ __launch_bounds__(256)
void conv_fused(const void* __restrict__ nf,              // [N][12][64]
                const unsigned* __restrict__ dflag,
                int prepped,                              // 1: nf canonical bf16
                const int* __restrict__ nidx,             // [N][12]
                const __hip_bfloat16* __restrict__ xay,   // [N][1024]: xa | y
                const __hip_bfloat16* __restrict__ b1l,   // [512]
                const __hip_bfloat16* __restrict__ w1TfL, // [512][64]
                __hip_bfloat16* __restrict__ ns)          // [N][512]
{
    __shared__ __align__(16) unsigned short sNF[48 * 72];   // 6.9 KB (pad holds idx)
    __shared__ __align__(16) unsigned short sZ[48 * ZS2];   // 25.7 KB
    // total 32640 B -> 32768 alloc -> 5 blocks/CU

    int tid = threadIdx.x;
    int ab  = blockIdx.x * 4;

    if (prepped || dflag[0] == 0u) {
        const __hip_bfloat16* nfB = (const __hip_bfloat16*)nf;
        for (int i = tid; i < 48 * 8; i += 256) {
            int r = i >> 3, ch = i & 7;
            uint4 v = *(const uint4*)(nfB + (size_t)(ab * 12 + r) * 64 + ch * 8);
            *(uint4*)(&sNF[r * 72 + ch * 8]) = v;
        }
    } else {
        const float* nfF = (const float*)nf;
        for (int i = tid; i < 48 * 8; i += 256) {
            int r = i >> 3, ch = i & 7;
            const float* src = nfF + (size_t)(ab * 12 + r) * 64 + ch * 8;
            float4 v0 = *(const float4*)(src);
            float4 v1 = *(const float4*)(src + 4);
            unsigned short* d = &sNF[r * 72 + ch * 8];
            d[0] = f2bfbits(v0.x); d[1] = f2bfbits(v0.y);
            d[2] = f2bfbits(v0.z); d[3] = f2bfbits(v0.w);
            d[4] = f2bfbits(v1.x); d[5] = f2bfbits(v1.y);
            d[6] = f2bfbits(v1.z); d[7] = f2bfbits(v1.w);
        }
    }
    // neighbor idx into sNF row pad (elem 64; staging writes only elems 0..63;
    // byte offset (r*72+64)*2 = 144r+128 is 4B-aligned)
    if (tid < 48) *(int*)&sNF[tid * 72 + 64] = nidx[ab * 12 + tid];
    __syncthreads();

    int wave = tid >> 6, lane = tid & 63, q = lane >> 4, ln = lane & 15;
    int c0 = wave * 32;                    // MFMA: wave covers 32 cols of each tile
    int a = wave, half = lane >> 5, lc = lane & 31;  // epilogue mapping
    int n = ab + a;
    int zc = half * 128 + lc * 4;          // col within tile-pair

    for (int tp = 0; tp < 2; tp++) {
        if (tp) __syncthreads();           // prev epilogue done reading sZ
        int gc = tp * 256 + zc;

        // ---- vmem issue order matters: bfr FIRST (MFMA waits only on these,
        // vmcnt(14) leaves the gathers in flight), then the slow gathers.
        bf16x8 bfr[2][2][2];               // [t2][c2][ks]
#pragma unroll
        for (int t2 = 0; t2 < 2; t2++) {
            int cb = (tp * 2 + t2) * 128;
#pragma unroll
            for (int c2 = 0; c2 < 2; c2++)
#pragma unroll
                for (int ks = 0; ks < 2; ks++)
                    bfr[t2][c2][ks] = *(const bf16x8*)(w1TfL +
                        (size_t)(cb + c0 + c2 * 16 + ln) * 64 + ks * 32 + q * 8);
        }
        uint2 yy[12];
#pragma unroll
        for (int m = 0; m < 12; m++) {
            int gi = *(const int*)&sNF[(a * 12 + m) * 72 + 64];
            yy[m] = *(const uint2*)((const char*)xay +
                                    ((size_t)(unsigned)gi << 11) + 1024u + gc * 2);
        }
        uint2 xau = *(const uint2*)(xay + (size_t)n * 1024 + gc);
        uint2 b1u = *(const uint2*)(b1l + gc);

#pragma unroll
        for (int t2 = 0; t2 < 2; t2++) {
            f32x4 acc[3][2];
            for (int rt = 0; rt < 3; rt++)
                for (int c2 = 0; c2 < 2; c2++) acc[rt][c2] = (f32x4){0.f, 0.f, 0.f, 0.f};
            for (int rt = 0; rt < 3; rt++) {
                bf16x8 a0 = *(const bf16x8*)(&sNF[(rt * 16 + ln) * 72 + q * 8]);
                bf16x8 a1 = *(const bf16x8*)(&sNF[(rt * 16 + ln) * 72 + 32 + q * 8]);
                acc[rt][0] = __builtin_amdgcn_mfma_f32_16x16x32_bf16(a0, bfr[t2][0][0], acc[rt][0], 0, 0, 0);
                acc[rt][0] = __builtin_amdgcn_mfma_f32_16x16x32_bf16(a1, bfr[t2][0][1], acc[rt][0], 0, 0, 0);
                acc[rt][1] = __builtin_amdgcn_mfma_f32_16x16x32_bf16(a0, bfr[t2][1][0], acc[rt][1], 0, 0, 0);
                acc[rt][1] = __builtin_amdgcn_mfma_f32_16x16x32_bf16(a1, bfr[t2][1][1], acc[rt][1], 0, 0, 0);
            }
            for (int rt = 0; rt < 3; rt++)
                for (int c2 = 0; c2 < 2; c2++)
                    for (int r = 0; r < 4; r++)
                        sZ[(rt * 16 + q * 4 + r) * ZS2 + t2 * 128 + c0 + c2 * 16 + ln] =
                            f2bfbits(acc[rt][c2][r]);
        }
        __syncthreads();

        // epilogue: thread owns (atom=wave, 4 cols), loop m
        float xa0 = bfbits2f((unsigned short)(xau.x & 0xffff)) +
                    bfbits2f((unsigned short)(b1u.x & 0xffff));
        float xa1 = bfbits2f((unsigned short)(xau.x >> 16)) +
                    bfbits2f((unsigned short)(b1u.x >> 16));
        float xa2 = bfbits2f((unsigned short)(xau.y & 0xffff)) +
                    bfbits2f((unsigned short)(b1u.y & 0xffff));
        float xa3 = bfbits2f((unsigned short)(xau.y >> 16)) +
                    bfbits2f((unsigned short)(b1u.y >> 16));
        float r0 = 0.f, r1 = 0.f, r2 = 0.f, r3 = 0.f;
#pragma unroll
        for (int m = 0; m < 12; m++) {
            uint2 zz = *(const uint2*)(&sZ[(a * 12 + m) * ZS2 + zc]);
            float v0 = bfbits2f((unsigned short)(zz.x & 0xffff)) + xa0 +
                       bfbits2f((unsigned short)(yy[m].x & 0xffff));
            float v1 = bfbits2f((unsigned short)(zz.x >> 16)) + xa1 +
                       bfbits2f((unsigned short)(yy[m].x >> 16));
            float v2 = bfbits2f((unsigned short)(zz.y & 0xffff)) + xa2 +
                       bfbits2f((unsigned short)(yy[m].y & 0xffff));
            float v3 = bfbits2f((unsigned short)(zz.y >> 16)) + xa3 +
                       bfbits2f((unsigned short)(yy[m].y >> 16));
            if (m < 6) {
                v0 = fmaxf(v0, 0.f); v1 = fmaxf(v1, 0.f);
                v2 = fmaxf(v2, 0.f); v3 = fmaxf(v3, 0.f);
            } else {
                v0 = softplus_f(v0); v1 = softplus_f(v1);
                v2 = softplus_f(v2); v3 = softplus_f(v3);
            }
            r0 += v0; r1 += v1; r2 += v2; r3 += v3;
        }
        uint2 o;
        o.x = (unsigned)f2bfbits(r0) | ((unsigned)f2bfbits(r1) << 16);
        o.y = (unsigned)f2bfbits(r2) | ((unsigned)f2bfbits(r3) << 16);
        *(uint2*)(ns + (size_t)n * F2 + gc) = o;
    }
}

// ---------------- batchnorm apply (stats fused into h2 GEMM) -----------------
__global__ __launch_bounds__(256)
void bn_apply(const __hip_bfloat16* __restrict__ h2, const float* __restrict__ st,
              const __hip_bfloat16* __restrict__ x,
              const __hip_bfloat16* __restrict__ gamma,
              const __hip_bfloat16* __restrict__ beta,
              __hip_bfloat16* __restrict__ xo) {
    int i = (blockIdx.x * 256 + threadIdx.x) * 8;
    int c = i & 255;
    uint4 hv = *(const uint4*)(h2 + i);
    uint4 xv = *(const uint4*)(x + i);
    unsigned hw[4] = {hv.x, hv.y, hv.z, hv.w};
    unsigned xw[4] = {xv.x, xv.y, xv.z, xv.w};
    unsigned ow[4];
    float r[8];
#pragma unroll
    for (int k = 0; k < 8; k++) {
        int cc = c + k;
        float mu  = st[cc] * (1.f / 20000.f);
        float var = fmaxf(st[AF + cc] * (1.f / 20000.f) - mu * mu, 0.f);
        unsigned hh = hw[k >> 1], xx = xw[k >> 1];
        float h  = bfbits2f((unsigned short)((k & 1) ? (hh >> 16) : (hh & 0xffff)));
        float xf = bfbits2f((unsigned short)((k & 1) ? (xx >> 16) : (xx & 0xffff)));
        float t = (h - mu) * rsqrtf(var + BN_EPS) * bf2f(gamma[cc]) + bf2f(beta[cc]);
        r[k] = softplus_f(xf + t);
    }
#pragma unroll
    for (int k = 0; k < 4; k++)
        ow[k] = pack2bf(r[2 * k], r[2 * k + 1]);
    *(uint4*)(xo + i) = make_uint4(ow[0], ow[1], ow[2], ow[3]);
}

// ---------------- readout: segment mean + 2-layer MLP ------------------------
__global__ __launch_bounds__(256)
void readout(const __hip_bfloat16* __restrict__ x, const int* __restrict__ m1,
             const __hip_bfloat16* __restrict__ smalls,
             const unsigned* __restrict__ dflag,
             void* __restrict__ outp) {
    __shared__ float sc[AF + 4];
    __shared__ float sred[4];
    bool isf32 = dflag[0] != 0u;
    int b = blockIdx.x, tid = threadIdx.x;
    float s = 0.f;
    for (int j = 0; j < KK; j++) {
        int row = m1[b * KK + j];
        s += bf2f(x[(size_t)row * AF + tid]);
    }
    sc[tid] = softplus_f(s * (1.f / (float)KK));
    if (tid < 4) sc[AF + tid] = softplus_f(bf2f(smalls[OFF_M2 + b * 4 + tid]));
    __syncthreads();
    float acc = bf2f(smalls[OFF_FCB + tid]);
    for (int k = 0; k < AF + 4; k++) acc += sc[k] * bf2f(smalls[OFF_FCW + k * 256 + tid]);
    float h = softplus_f(acc);
    float v = h * bf2f(smalls[OFF_OW + tid]);
    for (int off = 32; off > 0; off >>= 1) v += __shfl_down(v, off);
    if ((tid & 63) == 0) sred[tid >> 6] = v;
    __syncthreads();
    if (tid == 0) {
        float o = sred[0] + sred[1] + sred[2] + sred[3] + bf2f(smalls[OFF_OB]);
        if (isf32) ((float*)outp)[b] = o;
        else       ((__hip_bfloat16*)outp)[b] = f2bf(o);
    }
}

// ---------------- host ------------------------------------------------------
extern "C" void kernel_launch(void* const* d_in, const int* in_sizes, int n_in,
                              void* d_out, int out_size, void* d_ws, size_t ws_size,
                              hipStream_t stream) {
    const void* atom_fea = d_in[0];
    const void* nbr_fea  = d_in[1];
    const int*  nbr_idx  = (const int*)d_in[2];
    const int*  m1_idx   = (const int*)d_in[3];
    /* d_in[4] seg_ids: unused */
    const void* m2_fea = d_in[5];
    const void* emb_w  = d_in[6];
    const void* emb_b  = d_in[7];
    const void* w1     = d_in[8];
    const void* b1     = d_in[9];
    const void* w2     = d_in[10];
    const void* b2     = d_in[11];
    const void* gamma  = d_in[12];
    const void* beta   = d_in[13];
    const void* fc_w   = d_in[14];
    const void* fc_b   = d_in[15];
    const void* out_w  = d_in[16];
    const void* out_b  = d_in[17];

    // ---- aliased workspace (~86 MB core + 30.7 MB optional nfb) ----
    char* ws = (char*)d_ws;
    size_t off = 0;
    auto alloc = [&](size_t bytes) -> char* {
        char* p = ws + off;
        off += (bytes + 255) & ~(size_t)255;
        return p;
    };
    __hip_bfloat16* w1T2   = (__hip_bfloat16*)alloc((size_t)S_W12 * 2);
    __hip_bfloat16* w1Tf   = (__hip_bfloat16*)alloc((size_t)S_W1F * 2);
    __hip_bfloat16* w2T    = (__hip_bfloat16*)alloc((size_t)S_W2 * 2);
    __hip_bfloat16* smalls = (__hip_bfloat16*)alloc((size_t)N_SMALL * 2);
    __hip_bfloat16* xb0    = (__hip_bfloat16*)alloc((size_t)N_PAD * AF * 2);   // padded rows
    __hip_bfloat16* xb1    = (__hip_bfloat16*)alloc((size_t)N_PAD * AF * 2);   // padded rows
    char*           regXY  = alloc((size_t)N_ATOM * 1024 * 2);
    char*           regZ   = alloc((size_t)N_PAD * F2 * 2);                    // padded rows
    float*          stats  = (float*)alloc((size_t)3 * 2 * AF * 4);
    unsigned*       dflag  = (unsigned*)alloc(256);
    char*           nfb    = alloc((size_t)N_ATOM * 12 * 64 * 2);   // 30.72 MB
    int use_nfb = (ws_size >= off) ? 1 : 0;

    __hip_bfloat16* xay    = (__hip_bfloat16*)regXY;
    __hip_bfloat16* h2     = (__hip_bfloat16*)regXY;
    __hip_bfloat16* af_pad = (__hip_bfloat16*)(regXY + (size_t)N_ATOM * F2 * 2);  // 20.48MB free half
    __hip_bfloat16* embT   = (__hip_bfloat16*)regZ;
    __hip_bfloat16* nsb    = (__hip_bfloat16*)regZ;

    detect_dtype<<<1, 1, 0, stream>>>((const unsigned*)gamma, dflag);
    (void)hipMemsetAsync(stats, 0, (size_t)3 * 2 * AF * 4, stream);

    if (use_nfb)
        prep_nf<<<(N_ATOM * 12 * 64 / 4 + 255) / 256, 256, 0, stream>>>(nbr_fea, dflag,
                                                                        (unsigned*)nfb);
    prep_all<<<(S_TOT + 255) / 256, 256, 0, stream>>>(
        atom_fea, emb_w, w1, w2, b1, b2, gamma, beta, emb_b, fc_b, fc_w,
        out_w, out_b, m2_fea, dflag, af_pad, embT, w1T2, w1Tf, w2T, smalls);

    // embed: x = softplus(af_pad @ emb_w + emb_b)  (N=256 in one wide tile)
    dim3 g_emb((N_ATOM + 127) / 128, 1);
    gemm_kernel<true, 2><<<g_emb, 256, 0, stream>>>(af_pad, ORIG_P, embT, ORIG_P,
                                                    xb0, N_ATOM, AF, ORIG_P,
                                                    smalls + OFF_EMBB, 1, nullptr);

    const void* nf_conv = use_nfb ? (const void*)nfb : nbr_fea;

    __hip_bfloat16* xc = xb0;
    __hip_bfloat16* xn = xb1;
    for (int l = 0; l < 3; l++) {
        dim3 gxy((N_ATOM + 127) / 128, 4);       // 256-wide tiles over N=1024
        gemm_kernel<true, 2><<<gxy, 256, 0, stream>>>(xc, AF, w1T2 + (size_t)l * 1024 * 256, 256,
                                                      xay, N_ATOM, 1024, AF, nullptr, 0, nullptr);
        conv_fused<<<N_ATOM / 4, 256, 0, stream>>>(nf_conv, dflag, use_nfb, nbr_idx, xay,
                                                   smalls + OFF_B1 + l * F2,
                                                   w1Tf + (size_t)l * 512 * 64, nsb);
        float* stl = stats + l * 2 * AF;
        dim3 gh2((N_ATOM + 127) / 128, 1);       // N=256 in one wide tile
        gemm_kernel<true, 2><<<gh2, 256, 0, stream>>>(nsb, F2, w2T + (size_t)l * AF * F2, F2,
                                                      h2, N_ATOM, AF, F2,
                                                      smalls + OFF_B2 + l * AF, 0, stl);
        bn_apply<<<(N_ATOM * AF / 8) / 256, 256, 0, stream>>>(h2, stl, xc,
                                                              smalls + OFF_GAM + l * AF,
                                                              smalls + OFF_BET + l * AF, xn);
        __hip_bfloat16* t = xc; xc = xn; xn = t;
    }
    readout<<<BB, 256, 0, stream>>>(xc, m1_idx, smalls, dflag, d_out);
}

// Round 11
// 641.824 us; speedup vs baseline: 1.0184x; 1.0184x over previous
//
#include <hip/hip_runtime.h>
#include <hip/hip_bf16.h>

// CrystalGraphConvNet fused pipeline for MI355X (gfx950).
// Inputs f32 (runtime-detected from gamma; bf16 path kept).
//
// u@w1 = x@W_a + x_gathered@W_n + nf@W_f. xay = x@[W_a|W_n] (one N=1024 GEMM);
// conv v11 (kept): per phase, bfr loads issue first, then yy gathers (vmcnt
// drains in issue order -> MFMA waits only on bfr); ~88.5us structural floor.
// gemm v6: NTILES=2 ONLY for xy (628 blocks >= 2.4/CU). Round-10 lesson:
// NTILES=2 on emb/h2 dropped those grids to 157 blocks < 256 CUs (39% of
// CUs idle, 2x work/block -> dispatch ~2x slower; +60us total). Grids must
// cover the machine. emb/h2 back to NTILES=1 (157x2 grid, = round-8 config).
// v4 coalesced C-store + v3 T3 dbuf kept.
// conv v9: neighbor idx in sNF row pad -> LDS 32768 -> 5 blocks/CU.
// v6-v8 lesson: keep bf16 sZ stride-268. A-side buffers padded to 20096
// rows (branchless staging); stats/stores keep the row<M guard.

#define N_ATOM 20000
#define N_PAD  20096    // 157*128, A-side row padding for branchless staging
#define AF     256
#define F2     512
#define ORIG   92
#define ORIG_P 96
#define BB     200
#define KK     50
#define BN_EPS 1e-5f
#define ZS2    268      // sZ row stride (bf16): 256 + 12 pad -> q-groups bank-spread
#define CTS    132      // gemm C-repack tile stride (shorts)

// canonical small-tensor block (bf16) element offsets
#define OFF_B1   0        // 3*512
#define OFF_B2   1536     // 3*256
#define OFF_GAM  2304     // 3*256
#define OFF_BET  3072     // 3*256
#define OFF_EMBB 3840     // 256
#define OFF_FCB  4096     // 256
#define OFF_FCW  4352     // 260*256
#define OFF_OW   70912    // 256
#define OFF_OB   71168    // 1
#define OFF_M2   71169    // 200*4
#define N_SMALL  71969

// prep_all segment sizes
#define S_AF   (N_ATOM * ORIG_P)
#define S_EMB  (AF * ORIG_P)
#define S_W12  (3 * 1024 * 256)
#define S_W1F  (3 * 512 * 64)
#define S_W2   (3 * AF * F2)
#define S_SM   N_SMALL
#define S_TOT  (S_AF + S_EMB + S_W12 + S_W1F + S_W2 + S_SM)

using bf16x8 = __attribute__((ext_vector_type(8))) short;
using f32x4  = __attribute__((ext_vector_type(4))) float;

__device__ __forceinline__ float bf2f(__hip_bfloat16 v) { return __bfloat162float(v); }
__device__ __forceinline__ __hip_bfloat16 f2bf(float v) { return __float2bfloat16(v); }
__device__ __forceinline__ unsigned short f2bfbits(float f) {   // RNE f32->bf16 bits
    unsigned u = __float_as_uint(f);
    u += 0x7fffu + ((u >> 16) & 1u);
    return (unsigned short)(u >> 16);
}
__device__ __forceinline__ float bfbits2f(unsigned short u) {
    return __uint_as_float(((unsigned)u) << 16);
}
// pack two f32 -> u32 of two RNE bf16. Bit-identical to f2bfbits pair.
// NOTE: v_cvt_pk_bf16_f32 is NOT RNE-equivalent (tried, failed correctness).
__device__ __forceinline__ unsigned pack2bf(float lo, float hi) {
    unsigned ul = __float_as_uint(lo);
    unsigned uh = __float_as_uint(hi);
    ul += 0x7fffu + ((ul >> 16) & 1u);
    uh += 0x7fffu + ((uh >> 16) & 1u);
    return __builtin_amdgcn_perm(uh, ul, 0x07060302u);
}
__device__ __forceinline__ float softplus_f(float x) {
    return fmaxf(x, 0.f) + __logf(1.f + __expf(-fabsf(x)));
}
__device__ __forceinline__ float ld_any(const void* p, long idx, bool isf32) {
    return isf32 ? ((const float*)p)[idx] : bf2f(((const __hip_bfloat16*)p)[idx]);
}

// ---------------- dtype detect ----------------------------------------------
__global__ void detect_dtype(const unsigned* __restrict__ gamma_raw,
                             unsigned* __restrict__ flag) {
    unsigned u = gamma_raw[0];              // 1.0f = 0x3F800000 ; bf16 pair = 0x3F803F80
    flag[0] = ((u & 0xFFFFu) == 0u) ? 1u : 0u;
}

// ---------------- prep: nf -> canonical bf16 (once per launch) ---------------
__global__ __launch_bounds__(256) void prep_nf(const void* __restrict__ nf,
                                               const unsigned* __restrict__ dflag,
                                               unsigned* __restrict__ out) {
    bool isf32 = dflag[0] != 0u;
    int idx = blockIdx.x * 256 + threadIdx.x;        // one per 4 elems
    if (idx >= N_ATOM * 12 * 64 / 4) return;
    if (isf32) {
        float4 v = ((const float4*)nf)[idx];
        out[idx * 2]     = pack2bf(v.x, v.y);
        out[idx * 2 + 1] = pack2bf(v.z, v.w);
    } else {
        ((uint2*)out)[idx] = ((const uint2*)nf)[idx];
    }
}

// ---------------- merged prep ------------------------------------------------
__global__ __launch_bounds__(256)
void prep_all(const void* af, const void* emb_w, const void* w1, const void* w2,
              const void* b1, const void* b2, const void* gam, const void* bet,
              const void* embb, const void* fcb, const void* fcw,
              const void* ow, const void* ob, const void* m2,
              const unsigned* __restrict__ dflag,
              __hip_bfloat16* __restrict__ af_pad, __hip_bfloat16* __restrict__ embT,
              __hip_bfloat16* __restrict__ w1T2, __hip_bfloat16* __restrict__ w1Tf,
              __hip_bfloat16* __restrict__ w2T, __hip_bfloat16* __restrict__ smalls) {
    bool isf32 = dflag[0] != 0u;
    int i = blockIdx.x * 256 + threadIdx.x;
    if (i < S_AF) {
        int r = i / ORIG_P, k = i - r * ORIG_P;
        af_pad[i] = (k < ORIG) ? f2bf(ld_any(af, (long)r * ORIG + k, isf32)) : f2bf(0.f);
        return;
    }
    i -= S_AF;
    if (i < S_EMB) {
        int n = i / ORIG_P, k = i - n * ORIG_P;
        embT[i] = (k < ORIG) ? f2bf(ld_any(emb_w, (long)k * AF + n, isf32)) : f2bf(0.f);
        return;
    }
    i -= S_EMB;
    if (i < S_W12) {
        int l = i / (1024 * 256); int rem = i - l * (1024 * 256);
        int c = rem / 256, k = rem - c * 256;
        long src = (c < 512) ? ((long)(l * 576 + k) * F2 + c)
                             : ((long)(l * 576 + 256 + k) * F2 + (c - 512));
        w1T2[i] = f2bf(ld_any(w1, src, isf32));
        return;
    }
    i -= S_W12;
    if (i < S_W1F) {
        int l = i / (512 * 64); int rem = i - l * (512 * 64);
        int c = rem / 64, k = rem - c * 64;
        w1Tf[i] = f2bf(ld_any(w1, (long)(l * 576 + 512 + k) * F2 + c, isf32));
        return;
    }
    i -= S_W1F;
    if (i < S_W2) {
        int l = i / (AF * F2); int rem = i - l * (AF * F2);
        int n = rem / F2, k = rem - n * F2;
        w2T[i] = f2bf(ld_any(w2, (long)(l * F2 + k) * AF + n, isf32));
        return;
    }
    i -= S_W2;
    if (i >= S_SM) return;
    float v;
    if      (i < OFF_B2)   v = ld_any(b1,   i - OFF_B1,  isf32);
    else if (i < OFF_GAM)  v = ld_any(b2,   i - OFF_B2,  isf32);
    else if (i < OFF_BET)  v = ld_any(gam,  i - OFF_GAM, isf32);
    else if (i < OFF_EMBB) v = ld_any(bet,  i - OFF_BET, isf32);
    else if (i < OFF_FCB)  v = ld_any(embb, i - OFF_EMBB,isf32);
    else if (i < OFF_OW)   v = (i < OFF_FCW) ? ld_any(fcb, i - OFF_FCB, isf32)
                                             : ld_any(fcw, i - OFF_FCW, isf32);
    else if (i < OFF_OB)   v = ld_any(ow,   i - OFF_OW,  isf32);
    else if (i < OFF_M2)   v = ld_any(ob,   i - OFF_OB,  isf32);
    else                   v = ld_any(m2,   i - OFF_M2,  isf32);
    smalls[i] = f2bf(v);
}

// ---------------- generic MFMA GEMM: C = act(A @ B + bias) -------------------
// Output tile 128 x (128*NTILES) per block. T3 dbuf (one barrier/K-step) +
// per-ct LDS-repack coalesced C-store. sMem union: staging (2 bufs x
// (A 4096 + B 4096*NTILES) shorts) vs C-repack (128*CTS shorts).
// A must have >= ceil(M/128)*128 readable rows; stats/stores guard row<M.
// GRID RULE: blocks = gridDim.x*gridDim.y must be >= ~2x CU count (256);
// NTILES=2 only where the N-extent keeps the grid large (xy: 628 blocks).
template <bool OUT_BF16, int NTILES>
__global__ __launch_bounds__(256)
void gemm_kernel(const __hip_bfloat16* __restrict__ A, int lda,
                 const __hip_bfloat16* __restrict__ BT, int ldb,
                 void* __restrict__ Cp, int M, int ldc, int K,
                 const __hip_bfloat16* __restrict__ bias, int act,
                 float* __restrict__ st) {
    constexpr int BUFS = 4096 * (1 + NTILES);          // shorts per dbuf slot
    constexpr int SMEMN = (2 * BUFS > 128 * CTS) ? 2 * BUFS : 128 * CTS;
    __shared__ __align__(16) unsigned short sMem[SMEMN];
    __shared__ float sS[128 * NTILES], sS2[128 * NTILES];
    int tid  = threadIdx.x;
    int mt   = blockIdx.x, nt = blockIdx.y;
    int wave = tid >> 6, lane = tid & 63, q = lane >> 4, ln = lane & 15;
    int wr   = wave >> 1, wc = wave & 1;

    if (st) for (int i = tid; i < 128 * NTILES; i += 256) { sS[i] = 0.f; sS2[i] = 0.f; }

    const __hip_bfloat16* Abase = A + (size_t)mt * 128 * lda;
    const __hip_bfloat16* Bbase = BT + (size_t)nt * (128 * NTILES) * ldb;

    auto stage = [&](int buf, int k0) {
        const __hip_bfloat16* Ab = Abase + k0;
        const __hip_bfloat16* Bb = Bbase + k0;
        unsigned short* sAb = sMem + buf * BUFS;
        unsigned short* sBb = sAb + 4096;
#pragma unroll
        for (int jj = 0; jj < 2; jj++) {
            int idx = jj * 256 + tid;
            int r = idx >> 2, c = (idx & 3) * 8;
            __builtin_amdgcn_global_load_lds(
                (const __attribute__((address_space(1))) void*)(Ab + (size_t)r * lda + c),
                (__attribute__((address_space(3))) void*)(sAb + (jj * 256 + wave * 64) * 8),
                16, 0, 0);
        }
#pragma unroll
        for (int jj = 0; jj < 2 * NTILES; jj++) {
            int idx = jj * 256 + tid;
            int r = idx >> 2, c = (idx & 3) * 8;
            __builtin_amdgcn_global_load_lds(
                (const __attribute__((address_space(1))) void*)(Bb + (size_t)r * ldb + c),
                (__attribute__((address_space(3))) void*)(sBb + (jj * 256 + wave * 64) * 8),
                16, 0, 0);
        }
    };

    f32x4 acc[NTILES][4][4];
#pragma unroll
    for (int ct = 0; ct < NTILES; ct++)
        for (int i = 0; i < 4; i++)
            for (int j = 0; j < 4; j++) acc[ct][i][j] = (f32x4){0.f, 0.f, 0.f, 0.f};

    stage(0, 0);
    __syncthreads();                       // drains tile-0 DMA, syncs all waves
    int cur = 0;
    for (int k0 = 0; k0 < K; k0 += 32) {
        if (k0 + 32 < K) stage(cur ^ 1, k0 + 32);      // next tile in flight
        const unsigned short* sAc = sMem + cur * BUFS;
        const unsigned short* sBc = sAc + 4096;
        bf16x8 af[4];
#pragma unroll
        for (int i = 0; i < 4; i++)
            af[i] = *(const bf16x8*)(&sAc[(wr * 64 + i * 16 + ln) * 32 + q * 8]);
#pragma unroll
        for (int ct = 0; ct < NTILES; ct++) {
            bf16x8 bf[4];
#pragma unroll
            for (int j = 0; j < 4; j++)
                bf[j] = *(const bf16x8*)(&sBc[(ct * 128 + wc * 64 + j * 16 + ln) * 32 + q * 8]);
#pragma unroll
            for (int i = 0; i < 4; i++)
#pragma unroll
                for (int j = 0; j < 4; j++)
                    acc[ct][i][j] = __builtin_amdgcn_mfma_f32_16x16x32_bf16(af[i], bf[j], acc[ct][i][j], 0, 0, 0);
        }
        __syncthreads();                   // drains next-tile DMA + readers done
        cur ^= 1;
    }

    if constexpr (OUT_BF16) {
#pragma unroll
        for (int ct = 0; ct < NTILES; ct++) {
            if (ct) __syncthreads();       // prev store pass LDS reads done
            // phase 1: values -> sMem C-tile [128][CTS]
            for (int j = 0; j < 4; j++) {
                int cl  = wc * 64 + j * 16 + ln;
                int col = nt * (128 * NTILES) + ct * 128 + cl;
                float bv = bias ? bf2f(bias[col]) : 0.f;
                float ls = 0.f, ls2 = 0.f;
                for (int i = 0; i < 4; i++) {
                    for (int r = 0; r < 4; r++) {
                        int rl = wr * 64 + i * 16 + q * 4 + r;
                        float v = acc[ct][i][j][r] + bv;
                        if (st && mt * 128 + rl < M) { ls += v; ls2 += v * v; }
                        if (act == 1) v = softplus_f(v);
                        sMem[rl * CTS + cl] = f2bfbits(v);
                    }
                }
                if (st) { atomicAdd(&sS[ct * 128 + cl], ls); atomicAdd(&sS2[ct * 128 + cl], ls2); }
            }
            __syncthreads();
            // phase 2: coalesced stores — 16 lanes = one 256B row run.
#pragma unroll
            for (int it = 0; it < 8; it++) {
                int fi = it * 256 + tid;
                int rl = fi >> 4, c8 = (fi & 15) * 8;
                int row = mt * 128 + rl;
                if (row < M) {
                    uint4 v = *(const uint4*)(&sMem[rl * CTS + c8]);
                    *(uint4*)((__hip_bfloat16*)Cp + (size_t)row * ldc +
                              nt * (128 * NTILES) + ct * 128 + c8) = v;
                }
            }
        }
        if (st) {
            for (int i = tid; i < 128 * NTILES; i += 256) {
                int col = nt * (128 * NTILES) + i;
                atomicAdd(&st[col], sS[i]);
                atomicAdd(&st[AF + col], sS2[i]);
            }
        }
    } else {
        for (int ct = 0; ct < NTILES; ct++) {
            for (int j = 0; j < 4; j++) {
                int cl  = wc * 64 + j * 16 + ln;
                int col = nt * (128 * NTILES) + ct * 128 + cl;
                float bv = bias ? bf2f(bias[col]) : 0.f;
                for (int i = 0; i < 4; i++) {
                    for (int r = 0; r < 4; r++) {
                        int row = mt * 128 + wr * 64 + i * 16 + q * 4 + r;
                        if (row >= M) continue;
                        float v = acc[ct][i][j][r] + bv;
                        if (act == 1) v = softplus_f(v);
                        ((float*)Cp)[(size_t)row * ldc + col] = v;
                    }
                }
            }
        }
    }
}

// ---------------- fused conv v11 --------------------------------------------
// 4 atoms/block, 5000 blocks. Per phase (256 cols): issue bfr (both halves)
// FIRST, then yy/xau/b1u gathers -> MFMA (waits only on bfr, gathers stay in
// flight) -> z to LDS -> barrier -> epilogue consumes gather regs.
// Neighbor idx lives in sNF's per-row pad (elem 64) -> LDS fits 5 blocks/CU.
__global__ __launch_bounds__(256)
void conv_fused(const void* __restrict__ nf,              // [N][12][64]
                const unsigned* __restrict__ dflag,
                int prepped,                              // 1: nf canonical bf16
                const int* __restrict__ nidx,             // [N][12]
                const __hip_bfloat16* __restrict__ xay,   // [N][1024]: xa | y
                const __hip_bfloat16* __restrict__ b1l,   // [512]
                const __hip_bfloat16* __restrict__ w1TfL, // [512][64]
                __hip_bfloat16* __restrict__ ns)          // [N][512]
{
    __shared__ __align__(16) unsigned short sNF[48 * 72];   // 6.9 KB (pad holds idx)
    __shared__ __align__(16) unsigned short sZ[48 * ZS2];   // 25.7 KB
    // total 32640 B -> 32768 alloc -> 5 blocks/CU

    int tid = threadIdx.x;
    int ab  = blockIdx.x * 4;

    if (prepped || dflag[0] == 0u) {
        const __hip_bfloat16* nfB = (const __hip_bfloat16*)nf;
        for (int i = tid; i < 48 * 8; i += 256) {
            int r = i >> 3, ch = i & 7;
            uint4 v = *(const uint4*)(nfB + (size_t)(ab * 12 + r) * 64 + ch * 8);
            *(uint4*)(&sNF[r * 72 + ch * 8]) = v;
        }
    } else {
        const float* nfF = (const float*)nf;
        for (int i = tid; i < 48 * 8; i += 256) {
            int r = i >> 3, ch = i & 7;
            const float* src = nfF + (size_t)(ab * 12 + r) * 64 + ch * 8;
            float4 v0 = *(const float4*)(src);
            float4 v1 = *(const float4*)(src + 4);
            unsigned short* d = &sNF[r * 72 + ch * 8];
            d[0] = f2bfbits(v0.x); d[1] = f2bfbits(v0.y);
            d[2] = f2bfbits(v0.z); d[3] = f2bfbits(v0.w);
            d[4] = f2bfbits(v1.x); d[5] = f2bfbits(v1.y);
            d[6] = f2bfbits(v1.z); d[7] = f2bfbits(v1.w);
        }
    }
    // neighbor idx into sNF row pad (elem 64; staging writes only elems 0..63;
    // byte offset (r*72+64)*2 = 144r+128 is 4B-aligned)
    if (tid < 48) *(int*)&sNF[tid * 72 + 64] = nidx[ab * 12 + tid];
    __syncthreads();

    int wave = tid >> 6, lane = tid & 63, q = lane >> 4, ln = lane & 15;
    int c0 = wave * 32;                    // MFMA: wave covers 32 cols of each tile
    int a = wave, half = lane >> 5, lc = lane & 31;  // epilogue mapping
    int n = ab + a;
    int zc = half * 128 + lc * 4;          // col within tile-pair

    for (int tp = 0; tp < 2; tp++) {
        if (tp) __syncthreads();           // prev epilogue done reading sZ
        int gc = tp * 256 + zc;

        // ---- vmem issue order matters: bfr FIRST (MFMA waits only on these,
        // vmcnt(14) leaves the gathers in flight), then the slow gathers.
        bf16x8 bfr[2][2][2];               // [t2][c2][ks]
#pragma unroll
        for (int t2 = 0; t2 < 2; t2++) {
            int cb = (tp * 2 + t2) * 128;
#pragma unroll
            for (int c2 = 0; c2 < 2; c2++)
#pragma unroll
                for (int ks = 0; ks < 2; ks++)
                    bfr[t2][c2][ks] = *(const bf16x8*)(w1TfL +
                        (size_t)(cb + c0 + c2 * 16 + ln) * 64 + ks * 32 + q * 8);
        }
        uint2 yy[12];
#pragma unroll
        for (int m = 0; m < 12; m++) {
            int gi = *(const int*)&sNF[(a * 12 + m) * 72 + 64];
            yy[m] = *(const uint2*)((const char*)xay +
                                    ((size_t)(unsigned)gi << 11) + 1024u + gc * 2);
        }
        uint2 xau = *(const uint2*)(xay + (size_t)n * 1024 + gc);
        uint2 b1u = *(const uint2*)(b1l + gc);

#pragma unroll
        for (int t2 = 0; t2 < 2; t2++) {
            f32x4 acc[3][2];
            for (int rt = 0; rt < 3; rt++)
                for (int c2 = 0; c2 < 2; c2++) acc[rt][c2] = (f32x4){0.f, 0.f, 0.f, 0.f};
            for (int rt = 0; rt < 3; rt++) {
                bf16x8 a0 = *(const bf16x8*)(&sNF[(rt * 16 + ln) * 72 + q * 8]);
                bf16x8 a1 = *(const bf16x8*)(&sNF[(rt * 16 + ln) * 72 + 32 + q * 8]);
                acc[rt][0] = __builtin_amdgcn_mfma_f32_16x16x32_bf16(a0, bfr[t2][0][0], acc[rt][0], 0, 0, 0);
                acc[rt][0] = __builtin_amdgcn_mfma_f32_16x16x32_bf16(a1, bfr[t2][0][1], acc[rt][0], 0, 0, 0);
                acc[rt][1] = __builtin_amdgcn_mfma_f32_16x16x32_bf16(a0, bfr[t2][1][0], acc[rt][1], 0, 0, 0);
                acc[rt][1] = __builtin_amdgcn_mfma_f32_16x16x32_bf16(a1, bfr[t2][1][1], acc[rt][1], 0, 0, 0);
            }
            for (int rt = 0; rt < 3; rt++)
                for (int c2 = 0; c2 < 2; c2++)
                    for (int r = 0; r < 4; r++)
                        sZ[(rt * 16 + q * 4 + r) * ZS2 + t2 * 128 + c0 + c2 * 16 + ln] =
                            f2bfbits(acc[rt][c2][r]);
        }
        __syncthreads();

        // epilogue: thread owns (atom=wave, 4 cols), loop m
        float xa0 = bfbits2f((unsigned short)(xau.x & 0xffff)) +
                    bfbits2f((unsigned short)(b1u.x & 0xffff));
        float xa1 = bfbits2f((unsigned short)(xau.x >> 16)) +
                    bfbits2f((unsigned short)(b1u.x >> 16));
        float xa2 = bfbits2f((unsigned short)(xau.y & 0xffff)) +
                    bfbits2f((unsigned short)(b1u.y & 0xffff));
        float xa3 = bfbits2f((unsigned short)(xau.y >> 16)) +
                    bfbits2f((unsigned short)(b1u.y >> 16));
        float r0 = 0.f, r1 = 0.f, r2 = 0.f, r3 = 0.f;
#pragma unroll
        for (int m = 0; m < 12; m++) {
            uint2 zz = *(const uint2*)(&sZ[(a * 12 + m) * ZS2 + zc]);
            float v0 = bfbits2f((unsigned short)(zz.x & 0xffff)) + xa0 +
                       bfbits2f((unsigned short)(yy[m].x & 0xffff));
            float v1 = bfbits2f((unsigned short)(zz.x >> 16)) + xa1 +
                       bfbits2f((unsigned short)(yy[m].x >> 16));
            float v2 = bfbits2f((unsigned short)(zz.y & 0xffff)) + xa2 +
                       bfbits2f((unsigned short)(yy[m].y & 0xffff));
            float v3 = bfbits2f((unsigned short)(zz.y >> 16)) + xa3 +
                       bfbits2f((unsigned short)(yy[m].y >> 16));
            if (m < 6) {
                v0 = fmaxf(v0, 0.f); v1 = fmaxf(v1, 0.f);
                v2 = fmaxf(v2, 0.f); v3 = fmaxf(v3, 0.f);
            } else {
                v0 = softplus_f(v0); v1 = softplus_f(v1);
                v2 = softplus_f(v2); v3 = softplus_f(v3);
            }
            r0 += v0; r1 += v1; r2 += v2; r3 += v3;
        }
        uint2 o;
        o.x = (unsigned)f2bfbits(r0) | ((unsigned)f2bfbits(r1) << 16);
        o.y = (unsigned)f2bfbits(r2) | ((unsigned)f2bfbits(r3) << 16);
        *(uint2*)(ns + (size_t)n * F2 + gc) = o;
    }
}

// ---------------- batchnorm apply (stats fused into h2 GEMM) -----------------
__global__ __launch_bounds__(256)
void bn_apply(const __hip_bfloat16* __restrict__ h2, const float* __restrict__ st,
              const __hip_bfloat16* __restrict__ x,
              const __hip_bfloat16* __restrict__ gamma,
              const __hip_bfloat16* __restrict__ beta,
              __hip_bfloat16* __restrict__ xo) {
    int i = (blockIdx.x * 256 + threadIdx.x) * 8;
    int c = i & 255;
    uint4 hv = *(const uint4*)(h2 + i);
    uint4 xv = *(const uint4*)(x + i);
    unsigned hw[4] = {hv.x, hv.y, hv.z, hv.w};
    unsigned xw[4] = {xv.x, xv.y, xv.z, xv.w};
    unsigned ow[4];
    float r[8];
#pragma unroll
    for (int k = 0; k < 8; k++) {
        int cc = c + k;
        float mu  = st[cc] * (1.f / 20000.f);
        float var = fmaxf(st[AF + cc] * (1.f / 20000.f) - mu * mu, 0.f);
        unsigned hh = hw[k >> 1], xx = xw[k >> 1];
        float h  = bfbits2f((unsigned short)((k & 1) ? (hh >> 16) : (hh & 0xffff)));
        float xf = bfbits2f((unsigned short)((k & 1) ? (xx >> 16) : (xx & 0xffff)));
        float t = (h - mu) * rsqrtf(var + BN_EPS) * bf2f(gamma[cc]) + bf2f(beta[cc]);
        r[k] = softplus_f(xf + t);
    }
#pragma unroll
    for (int k = 0; k < 4; k++)
        ow[k] = pack2bf(r[2 * k], r[2 * k + 1]);
    *(uint4*)(xo + i) = make_uint4(ow[0], ow[1], ow[2], ow[3]);
}

// ---------------- readout: segment mean + 2-layer MLP ------------------------
__global__ __launch_bounds__(256)
void readout(const __hip_bfloat16* __restrict__ x, const int* __restrict__ m1,
             const __hip_bfloat16* __restrict__ smalls,
             const unsigned* __restrict__ dflag,
             void* __restrict__ outp) {
    __shared__ float sc[AF + 4];
    __shared__ float sred[4];
    bool isf32 = dflag[0] != 0u;
    int b = blockIdx.x, tid = threadIdx.x;
    float s = 0.f;
    for (int j = 0; j < KK; j++) {
        int row = m1[b * KK + j];
        s += bf2f(x[(size_t)row * AF + tid]);
    }
    sc[tid] = softplus_f(s * (1.f / (float)KK));
    if (tid < 4) sc[AF + tid] = softplus_f(bf2f(smalls[OFF_M2 + b * 4 + tid]));
    __syncthreads();
    float acc = bf2f(smalls[OFF_FCB + tid]);
    for (int k = 0; k < AF + 4; k++) acc += sc[k] * bf2f(smalls[OFF_FCW + k * 256 + tid]);
    float h = softplus_f(acc);
    float v = h * bf2f(smalls[OFF_OW + tid]);
    for (int off = 32; off > 0; off >>= 1) v += __shfl_down(v, off);
    if ((tid & 63) == 0) sred[tid >> 6] = v;
    __syncthreads();
    if (tid == 0) {
        float o = sred[0] + sred[1] + sred[2] + sred[3] + bf2f(smalls[OFF_OB]);
        if (isf32) ((float*)outp)[b] = o;
        else       ((__hip_bfloat16*)outp)[b] = f2bf(o);
    }
}

// ---------------- host ------------------------------------------------------
extern "C" void kernel_launch(void* const* d_in, const int* in_sizes, int n_in,
                              void* d_out, int out_size, void* d_ws, size_t ws_size,
                              hipStream_t stream) {
    const void* atom_fea = d_in[0];
    const void* nbr_fea  = d_in[1];
    const int*  nbr_idx  = (const int*)d_in[2];
    const int*  m1_idx   = (const int*)d_in[3];
    /* d_in[4] seg_ids: unused */
    const void* m2_fea = d_in[5];
    const void* emb_w  = d_in[6];
    const void* emb_b  = d_in[7];
    const void* w1     = d_in[8];
    const void* b1     = d_in[9];
    const void* w2     = d_in[10];
    const void* b2     = d_in[11];
    const void* gamma  = d_in[12];
    const void* beta   = d_in[13];
    const void* fc_w   = d_in[14];
    const void* fc_b   = d_in[15];
    const void* out_w  = d_in[16];
    const void* out_b  = d_in[17];

    // ---- aliased workspace (~86 MB core + 30.7 MB optional nfb) ----
    char* ws = (char*)d_ws;
    size_t off = 0;
    auto alloc = [&](size_t bytes) -> char* {
        char* p = ws + off;
        off += (bytes + 255) & ~(size_t)255;
        return p;
    };
    __hip_bfloat16* w1T2   = (__hip_bfloat16*)alloc((size_t)S_W12 * 2);
    __hip_bfloat16* w1Tf   = (__hip_bfloat16*)alloc((size_t)S_W1F * 2);
    __hip_bfloat16* w2T    = (__hip_bfloat16*)alloc((size_t)S_W2 * 2);
    __hip_bfloat16* smalls = (__hip_bfloat16*)alloc((size_t)N_SMALL * 2);
    __hip_bfloat16* xb0    = (__hip_bfloat16*)alloc((size_t)N_PAD * AF * 2);   // padded rows
    __hip_bfloat16* xb1    = (__hip_bfloat16*)alloc((size_t)N_PAD * AF * 2);   // padded rows
    char*           regXY  = alloc((size_t)N_ATOM * 1024 * 2);
    char*           regZ   = alloc((size_t)N_PAD * F2 * 2);                    // padded rows
    float*          stats  = (float*)alloc((size_t)3 * 2 * AF * 4);
    unsigned*       dflag  = (unsigned*)alloc(256);
    char*           nfb    = alloc((size_t)N_ATOM * 12 * 64 * 2);   // 30.72 MB
    int use_nfb = (ws_size >= off) ? 1 : 0;

    __hip_bfloat16* xay    = (__hip_bfloat16*)regXY;
    __hip_bfloat16* h2     = (__hip_bfloat16*)regXY;
    __hip_bfloat16* af_pad = (__hip_bfloat16*)(regXY + (size_t)N_ATOM * F2 * 2);  // 20.48MB free half
    __hip_bfloat16* embT   = (__hip_bfloat16*)regZ;
    __hip_bfloat16* nsb    = (__hip_bfloat16*)regZ;

    detect_dtype<<<1, 1, 0, stream>>>((const unsigned*)gamma, dflag);
    (void)hipMemsetAsync(stats, 0, (size_t)3 * 2 * AF * 4, stream);

    if (use_nfb)
        prep_nf<<<(N_ATOM * 12 * 64 / 4 + 255) / 256, 256, 0, stream>>>(nbr_fea, dflag,
                                                                        (unsigned*)nfb);
    prep_all<<<(S_TOT + 255) / 256, 256, 0, stream>>>(
        atom_fea, emb_w, w1, w2, b1, b2, gamma, beta, emb_b, fc_b, fc_w,
        out_w, out_b, m2_fea, dflag, af_pad, embT, w1T2, w1Tf, w2T, smalls);

    // embed: x = softplus(af_pad @ emb_w + emb_b)  (NTILES=1: 314 blocks)
    dim3 g_emb((N_ATOM + 127) / 128, 2);
    gemm_kernel<true, 1><<<g_emb, 256, 0, stream>>>(af_pad, ORIG_P, embT, ORIG_P,
                                                    xb0, N_ATOM, AF, ORIG_P,
                                                    smalls + OFF_EMBB, 1, nullptr);

    const void* nf_conv = use_nfb ? (const void*)nfb : nbr_fea;

    __hip_bfloat16* xc = xb0;
    __hip_bfloat16* xn = xb1;
    for (int l = 0; l < 3; l++) {
        dim3 gxy((N_ATOM + 127) / 128, 4);       // NTILES=2: 628 blocks over N=1024
        gemm_kernel<true, 2><<<gxy, 256, 0, stream>>>(xc, AF, w1T2 + (size_t)l * 1024 * 256, 256,
                                                      xay, N_ATOM, 1024, AF, nullptr, 0, nullptr);
        conv_fused<<<N_ATOM / 4, 256, 0, stream>>>(nf_conv, dflag, use_nfb, nbr_idx, xay,
                                                   smalls + OFF_B1 + l * F2,
                                                   w1Tf + (size_t)l * 512 * 64, nsb);
        float* stl = stats + l * 2 * AF;
        dim3 gh2((N_ATOM + 127) / 128, 2);       // NTILES=1: 314 blocks
        gemm_kernel<true, 1><<<gh2, 256, 0, stream>>>(nsb, F2, w2T + (size_t)l * AF * F2, F2,
                                                      h2, N_ATOM, AF, F2,
                                                      smalls + OFF_B2 + l * AF, 0, stl);
        bn_apply<<<(N_ATOM * AF / 8) / 256, 256, 0, stream>>>(h2, stl, xc,
                                                              smalls + OFF_GAM + l * AF,
                                                              smalls + OFF_BET + l * AF, xn);
        __hip_bfloat16* t = xc; xc = xn; xn = t;
    }
    readout<<<BB, 256, 0, stream>>>(xc, m1_idx, smalls, dflag, d_out);
}

// Round 12
// 592.242 us; speedup vs baseline: 1.1036x; 1.0837x over previous
//
#include <hip/hip_runtime.h>
#include <hip/hip_bf16.h>

// CrystalGraphConvNet fused pipeline for MI355X (gfx950).
// Inputs f32 (runtime-detected from gamma; bf16 path kept).
//
// FINAL CONFIG (best-measured ~590us): all GEMMs NTILES=1.
// Tile-width postmortem (r10/r11): NTILES=2 on emb/h2 starves the grid
// (157 blocks < 256 CUs, +60us); NTILES=2 on xy alone costs +50us via
// occupancy (128 acc VGPRs + 49KB LDS -> 2 waves/SIMD, 3 blocks/CU; the
// barrier'd K-loop needs cross-block TLP to hide DMA drain). Wide tiles
// are net-negative everywhere on this problem.
// conv v11: per phase, bfr loads issue first, then yy gathers (vmcnt drains
// in issue order -> MFMA waits only on bfr); ~88.5us structural floor
// (latency-bound epilogue gathers; 6 attacks all neutral).
// gemm v4: T3 dbuf (one barrier/K-step) + LDS-repack coalesced C-store.
// conv v9: neighbor idx in sNF row pad -> LDS 32768 -> 5 blocks/CU.
// v6-v8 lesson: keep bf16 sZ stride-268 (u32-packed sZ doubled epilogue LDS
// read bytes). A-side buffers padded to 20096 rows (branchless staging);
// stats/stores keep the row<M guard.
// NOTE: v_cvt_pk_bf16_f32 is NOT RNE-equivalent to the integer pack (v6
// failed correctness) — keep pack2bf / f2bfbits.

#define N_ATOM 20000
#define N_PAD  20096    // 157*128, A-side row padding for branchless staging
#define AF     256
#define F2     512
#define ORIG   92
#define ORIG_P 96
#define BB     200
#define KK     50
#define BN_EPS 1e-5f
#define ZS2    268      // sZ row stride (bf16): 256 + 12 pad -> q-groups bank-spread
#define CTS    132      // gemm C-repack tile stride (shorts)

// canonical small-tensor block (bf16) element offsets
#define OFF_B1   0        // 3*512
#define OFF_B2   1536     // 3*256
#define OFF_GAM  2304     // 3*256
#define OFF_BET  3072     // 3*256
#define OFF_EMBB 3840     // 256
#define OFF_FCB  4096     // 256
#define OFF_FCW  4352     // 260*256
#define OFF_OW   70912    // 256
#define OFF_OB   71168    // 1
#define OFF_M2   71169    // 200*4
#define N_SMALL  71969

// prep_all segment sizes
#define S_AF   (N_ATOM * ORIG_P)
#define S_EMB  (AF * ORIG_P)
#define S_W12  (3 * 1024 * 256)
#define S_W1F  (3 * 512 * 64)
#define S_W2   (3 * AF * F2)
#define S_SM   N_SMALL
#define S_TOT  (S_AF + S_EMB + S_W12 + S_W1F + S_W2 + S_SM)

using bf16x8 = __attribute__((ext_vector_type(8))) short;
using f32x4  = __attribute__((ext_vector_type(4))) float;

__device__ __forceinline__ float bf2f(__hip_bfloat16 v) { return __bfloat162float(v); }
__device__ __forceinline__ __hip_bfloat16 f2bf(float v) { return __float2bfloat16(v); }
__device__ __forceinline__ unsigned short f2bfbits(float f) {   // RNE f32->bf16 bits
    unsigned u = __float_as_uint(f);
    u += 0x7fffu + ((u >> 16) & 1u);
    return (unsigned short)(u >> 16);
}
__device__ __forceinline__ float bfbits2f(unsigned short u) {
    return __uint_as_float(((unsigned)u) << 16);
}
// pack two f32 -> u32 of two RNE bf16. Bit-identical to f2bfbits pair.
__device__ __forceinline__ unsigned pack2bf(float lo, float hi) {
    unsigned ul = __float_as_uint(lo);
    unsigned uh = __float_as_uint(hi);
    ul += 0x7fffu + ((ul >> 16) & 1u);
    uh += 0x7fffu + ((uh >> 16) & 1u);
    return __builtin_amdgcn_perm(uh, ul, 0x07060302u);
}
__device__ __forceinline__ float softplus_f(float x) {
    return fmaxf(x, 0.f) + __logf(1.f + __expf(-fabsf(x)));
}
__device__ __forceinline__ float ld_any(const void* p, long idx, bool isf32) {
    return isf32 ? ((const float*)p)[idx] : bf2f(((const __hip_bfloat16*)p)[idx]);
}

// ---------------- dtype detect ----------------------------------------------
__global__ void detect_dtype(const unsigned* __restrict__ gamma_raw,
                             unsigned* __restrict__ flag) {
    unsigned u = gamma_raw[0];              // 1.0f = 0x3F800000 ; bf16 pair = 0x3F803F80
    flag[0] = ((u & 0xFFFFu) == 0u) ? 1u : 0u;
}

// ---------------- prep: nf -> canonical bf16 (once per launch) ---------------
__global__ __launch_bounds__(256) void prep_nf(const void* __restrict__ nf,
                                               const unsigned* __restrict__ dflag,
                                               unsigned* __restrict__ out) {
    bool isf32 = dflag[0] != 0u;
    int idx = blockIdx.x * 256 + threadIdx.x;        // one per 4 elems
    if (idx >= N_ATOM * 12 * 64 / 4) return;
    if (isf32) {
        float4 v = ((const float4*)nf)[idx];
        out[idx * 2]     = pack2bf(v.x, v.y);
        out[idx * 2 + 1] = pack2bf(v.z, v.w);
    } else {
        ((uint2*)out)[idx] = ((const uint2*)nf)[idx];
    }
}

// ---------------- merged prep ------------------------------------------------
__global__ __launch_bounds__(256)
void prep_all(const void* af, const void* emb_w, const void* w1, const void* w2,
              const void* b1, const void* b2, const void* gam, const void* bet,
              const void* embb, const void* fcb, const void* fcw,
              const void* ow, const void* ob, const void* m2,
              const unsigned* __restrict__ dflag,
              __hip_bfloat16* __restrict__ af_pad, __hip_bfloat16* __restrict__ embT,
              __hip_bfloat16* __restrict__ w1T2, __hip_bfloat16* __restrict__ w1Tf,
              __hip_bfloat16* __restrict__ w2T, __hip_bfloat16* __restrict__ smalls) {
    bool isf32 = dflag[0] != 0u;
    int i = blockIdx.x * 256 + threadIdx.x;
    if (i < S_AF) {
        int r = i / ORIG_P, k = i - r * ORIG_P;
        af_pad[i] = (k < ORIG) ? f2bf(ld_any(af, (long)r * ORIG + k, isf32)) : f2bf(0.f);
        return;
    }
    i -= S_AF;
    if (i < S_EMB) {
        int n = i / ORIG_P, k = i - n * ORIG_P;
        embT[i] = (k < ORIG) ? f2bf(ld_any(emb_w, (long)k * AF + n, isf32)) : f2bf(0.f);
        return;
    }
    i -= S_EMB;
    if (i < S_W12) {
        int l = i / (1024 * 256); int rem = i - l * (1024 * 256);
        int c = rem / 256, k = rem - c * 256;
        long src = (c < 512) ? ((long)(l * 576 + k) * F2 + c)
                             : ((long)(l * 576 + 256 + k) * F2 + (c - 512));
        w1T2[i] = f2bf(ld_any(w1, src, isf32));
        return;
    }
    i -= S_W12;
    if (i < S_W1F) {
        int l = i / (512 * 64); int rem = i - l * (512 * 64);
        int c = rem / 64, k = rem - c * 64;
        w1Tf[i] = f2bf(ld_any(w1, (long)(l * 576 + 512 + k) * F2 + c, isf32));
        return;
    }
    i -= S_W1F;
    if (i < S_W2) {
        int l = i / (AF * F2); int rem = i - l * (AF * F2);
        int n = rem / F2, k = rem - n * F2;
        w2T[i] = f2bf(ld_any(w2, (long)(l * F2 + k) * AF + n, isf32));
        return;
    }
    i -= S_W2;
    if (i >= S_SM) return;
    float v;
    if      (i < OFF_B2)   v = ld_any(b1,   i - OFF_B1,  isf32);
    else if (i < OFF_GAM)  v = ld_any(b2,   i - OFF_B2,  isf32);
    else if (i < OFF_BET)  v = ld_any(gam,  i - OFF_GAM, isf32);
    else if (i < OFF_EMBB) v = ld_any(bet,  i - OFF_BET, isf32);
    else if (i < OFF_FCB)  v = ld_any(embb, i - OFF_EMBB,isf32);
    else if (i < OFF_OW)   v = (i < OFF_FCW) ? ld_any(fcb, i - OFF_FCB, isf32)
                                             : ld_any(fcw, i - OFF_FCW, isf32);
    else if (i < OFF_OB)   v = ld_any(ow,   i - OFF_OW,  isf32);
    else if (i < OFF_M2)   v = ld_any(ob,   i - OFF_OB,  isf32);
    else                   v = ld_any(m2,   i - OFF_M2,  isf32);
    smalls[i] = f2bf(v);
}

// ---------------- generic MFMA GEMM: C = act(A @ B + bias) -------------------
// Output tile 128 x (128*NTILES) per block; ALWAYS launch with NTILES=1
// (wide tiles measured net-negative: grid starvation or occupancy loss).
// T3 dbuf (one barrier/K-step) + per-ct LDS-repack coalesced C-store.
template <bool OUT_BF16, int NTILES>
__global__ __launch_bounds__(256)
void gemm_kernel(const __hip_bfloat16* __restrict__ A, int lda,
                 const __hip_bfloat16* __restrict__ BT, int ldb,
                 void* __restrict__ Cp, int M, int ldc, int K,
                 const __hip_bfloat16* __restrict__ bias, int act,
                 float* __restrict__ st) {
    constexpr int BUFS = 4096 * (1 + NTILES);          // shorts per dbuf slot
    constexpr int SMEMN = (2 * BUFS > 128 * CTS) ? 2 * BUFS : 128 * CTS;
    __shared__ __align__(16) unsigned short sMem[SMEMN];
    __shared__ float sS[128 * NTILES], sS2[128 * NTILES];
    int tid  = threadIdx.x;
    int mt   = blockIdx.x, nt = blockIdx.y;
    int wave = tid >> 6, lane = tid & 63, q = lane >> 4, ln = lane & 15;
    int wr   = wave >> 1, wc = wave & 1;

    if (st) for (int i = tid; i < 128 * NTILES; i += 256) { sS[i] = 0.f; sS2[i] = 0.f; }

    const __hip_bfloat16* Abase = A + (size_t)mt * 128 * lda;
    const __hip_bfloat16* Bbase = BT + (size_t)nt * (128 * NTILES) * ldb;

    auto stage = [&](int buf, int k0) {
        const __hip_bfloat16* Ab = Abase + k0;
        const __hip_bfloat16* Bb = Bbase + k0;
        unsigned short* sAb = sMem + buf * BUFS;
        unsigned short* sBb = sAb + 4096;
#pragma unroll
        for (int jj = 0; jj < 2; jj++) {
            int idx = jj * 256 + tid;
            int r = idx >> 2, c = (idx & 3) * 8;
            __builtin_amdgcn_global_load_lds(
                (const __attribute__((address_space(1))) void*)(Ab + (size_t)r * lda + c),
                (__attribute__((address_space(3))) void*)(sAb + (jj * 256 + wave * 64) * 8),
                16, 0, 0);
        }
#pragma unroll
        for (int jj = 0; jj < 2 * NTILES; jj++) {
            int idx = jj * 256 + tid;
            int r = idx >> 2, c = (idx & 3) * 8;
            __builtin_amdgcn_global_load_lds(
                (const __attribute__((address_space(1))) void*)(Bb + (size_t)r * ldb + c),
                (__attribute__((address_space(3))) void*)(sBb + (jj * 256 + wave * 64) * 8),
                16, 0, 0);
        }
    };

    f32x4 acc[NTILES][4][4];
#pragma unroll
    for (int ct = 0; ct < NTILES; ct++)
        for (int i = 0; i < 4; i++)
            for (int j = 0; j < 4; j++) acc[ct][i][j] = (f32x4){0.f, 0.f, 0.f, 0.f};

    stage(0, 0);
    __syncthreads();                       // drains tile-0 DMA, syncs all waves
    int cur = 0;
    for (int k0 = 0; k0 < K; k0 += 32) {
        if (k0 + 32 < K) stage(cur ^ 1, k0 + 32);      // next tile in flight
        const unsigned short* sAc = sMem + cur * BUFS;
        const unsigned short* sBc = sAc + 4096;
        bf16x8 af[4];
#pragma unroll
        for (int i = 0; i < 4; i++)
            af[i] = *(const bf16x8*)(&sAc[(wr * 64 + i * 16 + ln) * 32 + q * 8]);
#pragma unroll
        for (int ct = 0; ct < NTILES; ct++) {
            bf16x8 bf[4];
#pragma unroll
            for (int j = 0; j < 4; j++)
                bf[j] = *(const bf16x8*)(&sBc[(ct * 128 + wc * 64 + j * 16 + ln) * 32 + q * 8]);
#pragma unroll
            for (int i = 0; i < 4; i++)
#pragma unroll
                for (int j = 0; j < 4; j++)
                    acc[ct][i][j] = __builtin_amdgcn_mfma_f32_16x16x32_bf16(af[i], bf[j], acc[ct][i][j], 0, 0, 0);
        }
        __syncthreads();                   // drains next-tile DMA + readers done
        cur ^= 1;
    }

    if constexpr (OUT_BF16) {
#pragma unroll
        for (int ct = 0; ct < NTILES; ct++) {
            if (ct) __syncthreads();       // prev store pass LDS reads done
            // phase 1: values -> sMem C-tile [128][CTS]
            for (int j = 0; j < 4; j++) {
                int cl  = wc * 64 + j * 16 + ln;
                int col = nt * (128 * NTILES) + ct * 128 + cl;
                float bv = bias ? bf2f(bias[col]) : 0.f;
                float ls = 0.f, ls2 = 0.f;
                for (int i = 0; i < 4; i++) {
                    for (int r = 0; r < 4; r++) {
                        int rl = wr * 64 + i * 16 + q * 4 + r;
                        float v = acc[ct][i][j][r] + bv;
                        if (st && mt * 128 + rl < M) { ls += v; ls2 += v * v; }
                        if (act == 1) v = softplus_f(v);
                        sMem[rl * CTS + cl] = f2bfbits(v);
                    }
                }
                if (st) { atomicAdd(&sS[ct * 128 + cl], ls); atomicAdd(&sS2[ct * 128 + cl], ls2); }
            }
            __syncthreads();
            // phase 2: coalesced stores — 16 lanes = one 256B row run.
#pragma unroll
            for (int it = 0; it < 8; it++) {
                int fi = it * 256 + tid;
                int rl = fi >> 4, c8 = (fi & 15) * 8;
                int row = mt * 128 + rl;
                if (row < M) {
                    uint4 v = *(const uint4*)(&sMem[rl * CTS + c8]);
                    *(uint4*)((__hip_bfloat16*)Cp + (size_t)row * ldc +
                              nt * (128 * NTILES) + ct * 128 + c8) = v;
                }
            }
        }
        if (st) {
            for (int i = tid; i < 128 * NTILES; i += 256) {
                int col = nt * (128 * NTILES) + i;
                atomicAdd(&st[col], sS[i]);
                atomicAdd(&st[AF + col], sS2[i]);
            }
        }
    } else {
        for (int ct = 0; ct < NTILES; ct++) {
            for (int j = 0; j < 4; j++) {
                int cl  = wc * 64 + j * 16 + ln;
                int col = nt * (128 * NTILES) + ct * 128 + cl;
                float bv = bias ? bf2f(bias[col]) : 0.f;
                for (int i = 0; i < 4; i++) {
                    for (int r = 0; r < 4; r++) {
                        int row = mt * 128 + wr * 64 + i * 16 + q * 4 + r;
                        if (row >= M) continue;
                        float v = acc[ct][i][j][r] + bv;
                        if (act == 1) v = softplus_f(v);
                        ((float*)Cp)[(size_t)row * ldc + col] = v;
                    }
                }
            }
        }
    }
}

// ---------------- fused conv v11 --------------------------------------------
// 4 atoms/block, 5000 blocks. Per phase (256 cols): issue bfr (both halves)
// FIRST, then yy/xau/b1u gathers -> MFMA (waits only on bfr, gathers stay in
// flight) -> z to LDS -> barrier -> epilogue consumes gather regs.
// Neighbor idx lives in sNF's per-row pad (elem 64) -> LDS fits 5 blocks/CU.
__global__ __launch_bounds__(256)
void conv_fused(const void* __restrict__ nf,              // [N][12][64]
                const unsigned* __restrict__ dflag,
                int prepped,                              // 1: nf canonical bf16
                const int* __restrict__ nidx,             // [N][12]
                const __hip_bfloat16* __restrict__ xay,   // [N][1024]: xa | y
                const __hip_bfloat16* __restrict__ b1l,   // [512]
                const __hip_bfloat16* __restrict__ w1TfL, // [512][64]
                __hip_bfloat16* __restrict__ ns)          // [N][512]
{
    __shared__ __align__(16) unsigned short sNF[48 * 72];   // 6.9 KB (pad holds idx)
    __shared__ __align__(16) unsigned short sZ[48 * ZS2];   // 25.7 KB
    // total 32640 B -> 32768 alloc -> 5 blocks/CU

    int tid = threadIdx.x;
    int ab  = blockIdx.x * 4;

    if (prepped || dflag[0] == 0u) {
        const __hip_bfloat16* nfB = (const __hip_bfloat16*)nf;
        for (int i = tid; i < 48 * 8; i += 256) {
            int r = i >> 3, ch = i & 7;
            uint4 v = *(const uint4*)(nfB + (size_t)(ab * 12 + r) * 64 + ch * 8);
            *(uint4*)(&sNF[r * 72 + ch * 8]) = v;
        }
    } else {
        const float* nfF = (const float*)nf;
        for (int i = tid; i < 48 * 8; i += 256) {
            int r = i >> 3, ch = i & 7;
            const float* src = nfF + (size_t)(ab * 12 + r) * 64 + ch * 8;
            float4 v0 = *(const float4*)(src);
            float4 v1 = *(const float4*)(src + 4);
            unsigned short* d = &sNF[r * 72 + ch * 8];
            d[0] = f2bfbits(v0.x); d[1] = f2bfbits(v0.y);
            d[2] = f2bfbits(v0.z); d[3] = f2bfbits(v0.w);
            d[4] = f2bfbits(v1.x); d[5] = f2bfbits(v1.y);
            d[6] = f2bfbits(v1.z); d[7] = f2bfbits(v1.w);
        }
    }
    // neighbor idx into sNF row pad (elem 64; staging writes only elems 0..63;
    // byte offset (r*72+64)*2 = 144r+128 is 4B-aligned)
    if (tid < 48) *(int*)&sNF[tid * 72 + 64] = nidx[ab * 12 + tid];
    __syncthreads();

    int wave = tid >> 6, lane = tid & 63, q = lane >> 4, ln = lane & 15;
    int c0 = wave * 32;                    // MFMA: wave covers 32 cols of each tile
    int a = wave, half = lane >> 5, lc = lane & 31;  // epilogue mapping
    int n = ab + a;
    int zc = half * 128 + lc * 4;          // col within tile-pair

    for (int tp = 0; tp < 2; tp++) {
        if (tp) __syncthreads();           // prev epilogue done reading sZ
        int gc = tp * 256 + zc;

        // ---- vmem issue order matters: bfr FIRST (MFMA waits only on these,
        // vmcnt(14) leaves the gathers in flight), then the slow gathers.
        bf16x8 bfr[2][2][2];               // [t2][c2][ks]
#pragma unroll
        for (int t2 = 0; t2 < 2; t2++) {
            int cb = (tp * 2 + t2) * 128;
#pragma unroll
            for (int c2 = 0; c2 < 2; c2++)
#pragma unroll
                for (int ks = 0; ks < 2; ks++)
                    bfr[t2][c2][ks] = *(const bf16x8*)(w1TfL +
                        (size_t)(cb + c0 + c2 * 16 + ln) * 64 + ks * 32 + q * 8);
        }
        uint2 yy[12];
#pragma unroll
        for (int m = 0; m < 12; m++) {
            int gi = *(const int*)&sNF[(a * 12 + m) * 72 + 64];
            yy[m] = *(const uint2*)((const char*)xay +
                                    ((size_t)(unsigned)gi << 11) + 1024u + gc * 2);
        }
        uint2 xau = *(const uint2*)(xay + (size_t)n * 1024 + gc);
        uint2 b1u = *(const uint2*)(b1l + gc);

#pragma unroll
        for (int t2 = 0; t2 < 2; t2++) {
            f32x4 acc[3][2];
            for (int rt = 0; rt < 3; rt++)
                for (int c2 = 0; c2 < 2; c2++) acc[rt][c2] = (f32x4){0.f, 0.f, 0.f, 0.f};
            for (int rt = 0; rt < 3; rt++) {
                bf16x8 a0 = *(const bf16x8*)(&sNF[(rt * 16 + ln) * 72 + q * 8]);
                bf16x8 a1 = *(const bf16x8*)(&sNF[(rt * 16 + ln) * 72 + 32 + q * 8]);
                acc[rt][0] = __builtin_amdgcn_mfma_f32_16x16x32_bf16(a0, bfr[t2][0][0], acc[rt][0], 0, 0, 0);
                acc[rt][0] = __builtin_amdgcn_mfma_f32_16x16x32_bf16(a1, bfr[t2][0][1], acc[rt][0], 0, 0, 0);
                acc[rt][1] = __builtin_amdgcn_mfma_f32_16x16x32_bf16(a0, bfr[t2][1][0], acc[rt][1], 0, 0, 0);
                acc[rt][1] = __builtin_amdgcn_mfma_f32_16x16x32_bf16(a1, bfr[t2][1][1], acc[rt][1], 0, 0, 0);
            }
            for (int rt = 0; rt < 3; rt++)
                for (int c2 = 0; c2 < 2; c2++)
                    for (int r = 0; r < 4; r++)
                        sZ[(rt * 16 + q * 4 + r) * ZS2 + t2 * 128 + c0 + c2 * 16 + ln] =
                            f2bfbits(acc[rt][c2][r]);
        }
        __syncthreads();

        // epilogue: thread owns (atom=wave, 4 cols), loop m
        float xa0 = bfbits2f((unsigned short)(xau.x & 0xffff)) +
                    bfbits2f((unsigned short)(b1u.x & 0xffff));
        float xa1 = bfbits2f((unsigned short)(xau.x >> 16)) +
                    bfbits2f((unsigned short)(b1u.x >> 16));
        float xa2 = bfbits2f((unsigned short)(xau.y & 0xffff)) +
                    bfbits2f((unsigned short)(b1u.y & 0xffff));
        float xa3 = bfbits2f((unsigned short)(xau.y >> 16)) +
                    bfbits2f((unsigned short)(b1u.y >> 16));
        float r0 = 0.f, r1 = 0.f, r2 = 0.f, r3 = 0.f;
#pragma unroll
        for (int m = 0; m < 12; m++) {
            uint2 zz = *(const uint2*)(&sZ[(a * 12 + m) * ZS2 + zc]);
            float v0 = bfbits2f((unsigned short)(zz.x & 0xffff)) + xa0 +
                       bfbits2f((unsigned short)(yy[m].x & 0xffff));
            float v1 = bfbits2f((unsigned short)(zz.x >> 16)) + xa1 +
                       bfbits2f((unsigned short)(yy[m].x >> 16));
            float v2 = bfbits2f((unsigned short)(zz.y & 0xffff)) + xa2 +
                       bfbits2f((unsigned short)(yy[m].y & 0xffff));
            float v3 = bfbits2f((unsigned short)(zz.y >> 16)) + xa3 +
                       bfbits2f((unsigned short)(yy[m].y >> 16));
            if (m < 6) {
                v0 = fmaxf(v0, 0.f); v1 = fmaxf(v1, 0.f);
                v2 = fmaxf(v2, 0.f); v3 = fmaxf(v3, 0.f);
            } else {
                v0 = softplus_f(v0); v1 = softplus_f(v1);
                v2 = softplus_f(v2); v3 = softplus_f(v3);
            }
            r0 += v0; r1 += v1; r2 += v2; r3 += v3;
        }
        uint2 o;
        o.x = (unsigned)f2bfbits(r0) | ((unsigned)f2bfbits(r1) << 16);
        o.y = (unsigned)f2bfbits(r2) | ((unsigned)f2bfbits(r3) << 16);
        *(uint2*)(ns + (size_t)n * F2 + gc) = o;
    }
}

// ---------------- batchnorm apply (stats fused into h2 GEMM) -----------------
__global__ __launch_bounds__(256)
void bn_apply(const __hip_bfloat16* __restrict__ h2, const float* __restrict__ st,
              const __hip_bfloat16* __restrict__ x,
              const __hip_bfloat16* __restrict__ gamma,
              const __hip_bfloat16* __restrict__ beta,
              __hip_bfloat16* __restrict__ xo) {
    int i = (blockIdx.x * 256 + threadIdx.x) * 8;
    int c = i & 255;
    uint4 hv = *(const uint4*)(h2 + i);
    uint4 xv = *(const uint4*)(x + i);
    unsigned hw[4] = {hv.x, hv.y, hv.z, hv.w};
    unsigned xw[4] = {xv.x, xv.y, xv.z, xv.w};
    unsigned ow[4];
    float r[8];
#pragma unroll
    for (int k = 0; k < 8; k++) {
        int cc = c + k;
        float mu  = st[cc] * (1.f / 20000.f);
        float var = fmaxf(st[AF + cc] * (1.f / 20000.f) - mu * mu, 0.f);
        unsigned hh = hw[k >> 1], xx = xw[k >> 1];
        float h  = bfbits2f((unsigned short)((k & 1) ? (hh >> 16) : (hh & 0xffff)));
        float xf = bfbits2f((unsigned short)((k & 1) ? (xx >> 16) : (xx & 0xffff)));
        float t = (h - mu) * rsqrtf(var + BN_EPS) * bf2f(gamma[cc]) + bf2f(beta[cc]);
        r[k] = softplus_f(xf + t);
    }
#pragma unroll
    for (int k = 0; k < 4; k++)
        ow[k] = pack2bf(r[2 * k], r[2 * k + 1]);
    *(uint4*)(xo + i) = make_uint4(ow[0], ow[1], ow[2], ow[3]);
}

// ---------------- readout: segment mean + 2-layer MLP ------------------------
__global__ __launch_bounds__(256)
void readout(const __hip_bfloat16* __restrict__ x, const int* __restrict__ m1,
             const __hip_bfloat16* __restrict__ smalls,
             const unsigned* __restrict__ dflag,
             void* __restrict__ outp) {
    __shared__ float sc[AF + 4];
    __shared__ float sred[4];
    bool isf32 = dflag[0] != 0u;
    int b = blockIdx.x, tid = threadIdx.x;
    float s = 0.f;
    for (int j = 0; j < KK; j++) {
        int row = m1[b * KK + j];
        s += bf2f(x[(size_t)row * AF + tid]);
    }
    sc[tid] = softplus_f(s * (1.f / (float)KK));
    if (tid < 4) sc[AF + tid] = softplus_f(bf2f(smalls[OFF_M2 + b * 4 + tid]));
    __syncthreads();
    float acc = bf2f(smalls[OFF_FCB + tid]);
    for (int k = 0; k < AF + 4; k++) acc += sc[k] * bf2f(smalls[OFF_FCW + k * 256 + tid]);
    float h = softplus_f(acc);
    float v = h * bf2f(smalls[OFF_OW + tid]);
    for (int off = 32; off > 0; off >>= 1) v += __shfl_down(v, off);
    if ((tid & 63) == 0) sred[tid >> 6] = v;
    __syncthreads();
    if (tid == 0) {
        float o = sred[0] + sred[1] + sred[2] + sred[3] + bf2f(smalls[OFF_OB]);
        if (isf32) ((float*)outp)[b] = o;
        else       ((__hip_bfloat16*)outp)[b] = f2bf(o);
    }
}

// ---------------- host ------------------------------------------------------
extern "C" void kernel_launch(void* const* d_in, const int* in_sizes, int n_in,
                              void* d_out, int out_size, void* d_ws, size_t ws_size,
                              hipStream_t stream) {
    const void* atom_fea = d_in[0];
    const void* nbr_fea  = d_in[1];
    const int*  nbr_idx  = (const int*)d_in[2];
    const int*  m1_idx   = (const int*)d_in[3];
    /* d_in[4] seg_ids: unused */
    const void* m2_fea = d_in[5];
    const void* emb_w  = d_in[6];
    const void* emb_b  = d_in[7];
    const void* w1     = d_in[8];
    const void* b1     = d_in[9];
    const void* w2     = d_in[10];
    const void* b2     = d_in[11];
    const void* gamma  = d_in[12];
    const void* beta   = d_in[13];
    const void* fc_w   = d_in[14];
    const void* fc_b   = d_in[15];
    const void* out_w  = d_in[16];
    const void* out_b  = d_in[17];

    // ---- aliased workspace (~86 MB core + 30.7 MB optional nfb) ----
    char* ws = (char*)d_ws;
    size_t off = 0;
    auto alloc = [&](size_t bytes) -> char* {
        char* p = ws + off;
        off += (bytes + 255) & ~(size_t)255;
        return p;
    };
    __hip_bfloat16* w1T2   = (__hip_bfloat16*)alloc((size_t)S_W12 * 2);
    __hip_bfloat16* w1Tf   = (__hip_bfloat16*)alloc((size_t)S_W1F * 2);
    __hip_bfloat16* w2T    = (__hip_bfloat16*)alloc((size_t)S_W2 * 2);
    __hip_bfloat16* smalls = (__hip_bfloat16*)alloc((size_t)N_SMALL * 2);
    __hip_bfloat16* xb0    = (__hip_bfloat16*)alloc((size_t)N_PAD * AF * 2);   // padded rows
    __hip_bfloat16* xb1    = (__hip_bfloat16*)alloc((size_t)N_PAD * AF * 2);   // padded rows
    char*           regXY  = alloc((size_t)N_ATOM * 1024 * 2);
    char*           regZ   = alloc((size_t)N_PAD * F2 * 2);                    // padded rows
    float*          stats  = (float*)alloc((size_t)3 * 2 * AF * 4);
    unsigned*       dflag  = (unsigned*)alloc(256);
    char*           nfb    = alloc((size_t)N_ATOM * 12 * 64 * 2);   // 30.72 MB
    int use_nfb = (ws_size >= off) ? 1 : 0;

    __hip_bfloat16* xay    = (__hip_bfloat16*)regXY;
    __hip_bfloat16* h2     = (__hip_bfloat16*)regXY;
    __hip_bfloat16* af_pad = (__hip_bfloat16*)(regXY + (size_t)N_ATOM * F2 * 2);  // 20.48MB free half
    __hip_bfloat16* embT   = (__hip_bfloat16*)regZ;
    __hip_bfloat16* nsb    = (__hip_bfloat16*)regZ;

    detect_dtype<<<1, 1, 0, stream>>>((const unsigned*)gamma, dflag);
    (void)hipMemsetAsync(stats, 0, (size_t)3 * 2 * AF * 4, stream);

    if (use_nfb)
        prep_nf<<<(N_ATOM * 12 * 64 / 4 + 255) / 256, 256, 0, stream>>>(nbr_fea, dflag,
                                                                        (unsigned*)nfb);
    prep_all<<<(S_TOT + 255) / 256, 256, 0, stream>>>(
        atom_fea, emb_w, w1, w2, b1, b2, gamma, beta, emb_b, fc_b, fc_w,
        out_w, out_b, m2_fea, dflag, af_pad, embT, w1T2, w1Tf, w2T, smalls);

    // embed: x = softplus(af_pad @ emb_w + emb_b)  (314 blocks)
    dim3 g_emb((N_ATOM + 127) / 128, 2);
    gemm_kernel<true, 1><<<g_emb, 256, 0, stream>>>(af_pad, ORIG_P, embT, ORIG_P,
                                                    xb0, N_ATOM, AF, ORIG_P,
                                                    smalls + OFF_EMBB, 1, nullptr);

    const void* nf_conv = use_nfb ? (const void*)nfb : nbr_fea;

    __hip_bfloat16* xc = xb0;
    __hip_bfloat16* xn = xb1;
    for (int l = 0; l < 3; l++) {
        dim3 gxy((N_ATOM + 127) / 128, 8);       // 1256 blocks over N=1024
        gemm_kernel<true, 1><<<gxy, 256, 0, stream>>>(xc, AF, w1T2 + (size_t)l * 1024 * 256, 256,
                                                      xay, N_ATOM, 1024, AF, nullptr, 0, nullptr);
        conv_fused<<<N_ATOM / 4, 256, 0, stream>>>(nf_conv, dflag, use_nfb, nbr_idx, xay,
                                                   smalls + OFF_B1 + l * F2,
                                                   w1Tf + (size_t)l * 512 * 64, nsb);
        float* stl = stats + l * 2 * AF;
        dim3 gh2((N_ATOM + 127) / 128, 2);       // 314 blocks
        gemm_kernel<true, 1><<<gh2, 256, 0, stream>>>(nsb, F2, w2T + (size_t)l * AF * F2, F2,
                                                      h2, N_ATOM, AF, F2,
                                                      smalls + OFF_B2 + l * AF, 0, stl);
        bn_apply<<<(N_ATOM * AF / 8) / 256, 256, 0, stream>>>(h2, stl, xc,
                                                              smalls + OFF_GAM + l * AF,
                                                              smalls + OFF_BET + l * AF, xn);
        __hip_bfloat16* t = xc; xc = xn; xn = t;
    }
    readout<<<BB, 256, 0, stream>>>(xc, m1_idx, smalls, dflag, d_out);
}

// Round 13
// 570.344 us; speedup vs baseline: 1.1460x; 1.0384x over previous
//
#include <hip/hip_runtime.h>
#include <hip/hip_bf16.h>

// CrystalGraphConvNet fused pipeline for MI355X (gfx950).
// Inputs f32 (runtime-detected from gamma; bf16 path kept).
//
// gemm v7 = v4 (T3 dbuf + coalesced C-store, NTILES=1) + XCD-aware block
// swizzle (T1/m204 bijective): 1D grid; lid%8 = XCD (round-robin dispatch),
// wid = contiguous-range-per-XCD remap, mt = wid/ntB, nt = wid%ntB. Blocks
// sharing an A-tile (same mt, all nt) land on ONE XCD -> A fetched into that
// XCD's L2 once instead of ntB times (xy: 80MB -> ~10MB A traffic).
// Tile-width postmortem (r10/r11): NTILES=2 net-negative everywhere (grid
// starvation on emb/h2; occupancy loss on xy). Keep NTILES=1.
// conv v11: per phase, bfr loads issue first, then yy gathers (vmcnt drains
// in issue order -> MFMA waits only on bfr); ~89us structural floor.
// conv v9: neighbor idx in sNF row pad -> LDS 32768 -> 5 blocks/CU.
// v6-v8 lesson: keep bf16 sZ stride-268 (u32-packed sZ doubled epilogue LDS
// read bytes). A-side buffers padded to 20096 rows (branchless staging);
// stats/stores keep the row<M guard.
// NOTE: v_cvt_pk_bf16_f32 is NOT RNE-equivalent to the integer pack (v6
// failed correctness) — keep pack2bf / f2bfbits.

#define N_ATOM 20000
#define N_PAD  20096    // 157*128, A-side row padding for branchless staging
#define AF     256
#define F2     512
#define ORIG   92
#define ORIG_P 96
#define BB     200
#define KK     50
#define BN_EPS 1e-5f
#define ZS2    268      // sZ row stride (bf16): 256 + 12 pad -> q-groups bank-spread
#define CTS    132      // gemm C-repack tile stride (shorts)

// canonical small-tensor block (bf16) element offsets
#define OFF_B1   0        // 3*512
#define OFF_B2   1536     // 3*256
#define OFF_GAM  2304     // 3*256
#define OFF_BET  3072     // 3*256
#define OFF_EMBB 3840     // 256
#define OFF_FCB  4096     // 256
#define OFF_FCW  4352     // 260*256
#define OFF_OW   70912    // 256
#define OFF_OB   71168    // 1
#define OFF_M2   71169    // 200*4
#define N_SMALL  71969

// prep_all segment sizes
#define S_AF   (N_ATOM * ORIG_P)
#define S_EMB  (AF * ORIG_P)
#define S_W12  (3 * 1024 * 256)
#define S_W1F  (3 * 512 * 64)
#define S_W2   (3 * AF * F2)
#define S_SM   N_SMALL
#define S_TOT  (S_AF + S_EMB + S_W12 + S_W1F + S_W2 + S_SM)

using bf16x8 = __attribute__((ext_vector_type(8))) short;
using f32x4  = __attribute__((ext_vector_type(4))) float;

__device__ __forceinline__ float bf2f(__hip_bfloat16 v) { return __bfloat162float(v); }
__device__ __forceinline__ __hip_bfloat16 f2bf(float v) { return __float2bfloat16(v); }
__device__ __forceinline__ unsigned short f2bfbits(float f) {   // RNE f32->bf16 bits
    unsigned u = __float_as_uint(f);
    u += 0x7fffu + ((u >> 16) & 1u);
    return (unsigned short)(u >> 16);
}
__device__ __forceinline__ float bfbits2f(unsigned short u) {
    return __uint_as_float(((unsigned)u) << 16);
}
// pack two f32 -> u32 of two RNE bf16. Bit-identical to f2bfbits pair.
__device__ __forceinline__ unsigned pack2bf(float lo, float hi) {
    unsigned ul = __float_as_uint(lo);
    unsigned uh = __float_as_uint(hi);
    ul += 0x7fffu + ((ul >> 16) & 1u);
    uh += 0x7fffu + ((uh >> 16) & 1u);
    return __builtin_amdgcn_perm(uh, ul, 0x07060302u);
}
__device__ __forceinline__ float softplus_f(float x) {
    return fmaxf(x, 0.f) + __logf(1.f + __expf(-fabsf(x)));
}
__device__ __forceinline__ float ld_any(const void* p, long idx, bool isf32) {
    return isf32 ? ((const float*)p)[idx] : bf2f(((const __hip_bfloat16*)p)[idx]);
}

// ---------------- dtype detect ----------------------------------------------
__global__ void detect_dtype(const unsigned* __restrict__ gamma_raw,
                             unsigned* __restrict__ flag) {
    unsigned u = gamma_raw[0];              // 1.0f = 0x3F800000 ; bf16 pair = 0x3F803F80
    flag[0] = ((u & 0xFFFFu) == 0u) ? 1u : 0u;
}

// ---------------- prep: nf -> canonical bf16 (once per launch) ---------------
__global__ __launch_bounds__(256) void prep_nf(const void* __restrict__ nf,
                                               const unsigned* __restrict__ dflag,
                                               unsigned* __restrict__ out) {
    bool isf32 = dflag[0] != 0u;
    int idx = blockIdx.x * 256 + threadIdx.x;        // one per 4 elems
    if (idx >= N_ATOM * 12 * 64 / 4) return;
    if (isf32) {
        float4 v = ((const float4*)nf)[idx];
        out[idx * 2]     = pack2bf(v.x, v.y);
        out[idx * 2 + 1] = pack2bf(v.z, v.w);
    } else {
        ((uint2*)out)[idx] = ((const uint2*)nf)[idx];
    }
}

// ---------------- merged prep ------------------------------------------------
__global__ __launch_bounds__(256)
void prep_all(const void* af, const void* emb_w, const void* w1, const void* w2,
              const void* b1, const void* b2, const void* gam, const void* bet,
              const void* embb, const void* fcb, const void* fcw,
              const void* ow, const void* ob, const void* m2,
              const unsigned* __restrict__ dflag,
              __hip_bfloat16* __restrict__ af_pad, __hip_bfloat16* __restrict__ embT,
              __hip_bfloat16* __restrict__ w1T2, __hip_bfloat16* __restrict__ w1Tf,
              __hip_bfloat16* __restrict__ w2T, __hip_bfloat16* __restrict__ smalls) {
    bool isf32 = dflag[0] != 0u;
    int i = blockIdx.x * 256 + threadIdx.x;
    if (i < S_AF) {
        int r = i / ORIG_P, k = i - r * ORIG_P;
        af_pad[i] = (k < ORIG) ? f2bf(ld_any(af, (long)r * ORIG + k, isf32)) : f2bf(0.f);
        return;
    }
    i -= S_AF;
    if (i < S_EMB) {
        int n = i / ORIG_P, k = i - n * ORIG_P;
        embT[i] = (k < ORIG) ? f2bf(ld_any(emb_w, (long)k * AF + n, isf32)) : f2bf(0.f);
        return;
    }
    i -= S_EMB;
    if (i < S_W12) {
        int l = i / (1024 * 256); int rem = i - l * (1024 * 256);
        int c = rem / 256, k = rem - c * 256;
        long src = (c < 512) ? ((long)(l * 576 + k) * F2 + c)
                             : ((long)(l * 576 + 256 + k) * F2 + (c - 512));
        w1T2[i] = f2bf(ld_any(w1, src, isf32));
        return;
    }
    i -= S_W12;
    if (i < S_W1F) {
        int l = i / (512 * 64); int rem = i - l * (512 * 64);
        int c = rem / 64, k = rem - c * 64;
        w1Tf[i] = f2bf(ld_any(w1, (long)(l * 576 + 512 + k) * F2 + c, isf32));
        return;
    }
    i -= S_W1F;
    if (i < S_W2) {
        int l = i / (AF * F2); int rem = i - l * (AF * F2);
        int n = rem / F2, k = rem - n * F2;
        w2T[i] = f2bf(ld_any(w2, (long)(l * F2 + k) * AF + n, isf32));
        return;
    }
    i -= S_W2;
    if (i >= S_SM) return;
    float v;
    if      (i < OFF_B2)   v = ld_any(b1,   i - OFF_B1,  isf32);
    else if (i < OFF_GAM)  v = ld_any(b2,   i - OFF_B2,  isf32);
    else if (i < OFF_BET)  v = ld_any(gam,  i - OFF_GAM, isf32);
    else if (i < OFF_EMBB) v = ld_any(bet,  i - OFF_BET, isf32);
    else if (i < OFF_FCB)  v = ld_any(embb, i - OFF_EMBB,isf32);
    else if (i < OFF_OW)   v = (i < OFF_FCW) ? ld_any(fcb, i - OFF_FCB, isf32)
                                             : ld_any(fcw, i - OFF_FCW, isf32);
    else if (i < OFF_OB)   v = ld_any(ow,   i - OFF_OW,  isf32);
    else if (i < OFF_M2)   v = ld_any(ob,   i - OFF_OB,  isf32);
    else                   v = ld_any(m2,   i - OFF_M2,  isf32);
    smalls[i] = f2bf(v);
}

// ---------------- generic MFMA GEMM: C = act(A @ B + bias) -------------------
// 1D grid, XCD-swizzled (mt,nt): lid%8 = XCD (round-robin dispatch assumed;
// wrong assumption only costs locality, never correctness). Bijective remap
// (m204) gives each XCD a contiguous wid range; mt = wid/ntB -> each XCD owns
// whole mt-groups, so an A-tile is fetched into exactly one XCD L2.
// T3 dbuf (one barrier/K-step) + LDS-repack coalesced C-store. NTILES=1 only.
template <bool OUT_BF16, int NTILES>
__global__ __launch_bounds__(256)
void gemm_kernel(const __hip_bfloat16* __restrict__ A, int lda,
                 const __hip_bfloat16* __restrict__ BT, int ldb,
                 void* __restrict__ Cp, int M, int ldc, int K,
                 const __hip_bfloat16* __restrict__ bias, int act,
                 float* __restrict__ st, int ntB) {
    constexpr int BUFS = 4096 * (1 + NTILES);          // shorts per dbuf slot
    constexpr int SMEMN = (2 * BUFS > 128 * CTS) ? 2 * BUFS : 128 * CTS;
    __shared__ __align__(16) unsigned short sMem[SMEMN];
    __shared__ float sS[128 * NTILES], sS2[128 * NTILES];
    int tid  = threadIdx.x;
    // ---- XCD-aware bijective swizzle (T1/m204) ----
    int nwg = gridDim.x, lid = blockIdx.x;
    int per = nwg >> 3, rem = nwg & 7;
    int xcd = lid & 7, j = lid >> 3;
    int wid = (xcd < rem ? xcd * (per + 1) : rem * (per + 1) + (xcd - rem) * per) + j;
    int mt = wid / ntB, nt = wid % ntB;

    int wave = tid >> 6, lane = tid & 63, q = lane >> 4, ln = lane & 15;
    int wr   = wave >> 1, wc = wave & 1;

    if (st) for (int i = tid; i < 128 * NTILES; i += 256) { sS[i] = 0.f; sS2[i] = 0.f; }

    const __hip_bfloat16* Abase = A + (size_t)mt * 128 * lda;
    const __hip_bfloat16* Bbase = BT + (size_t)nt * (128 * NTILES) * ldb;

    auto stage = [&](int buf, int k0) {
        const __hip_bfloat16* Ab = Abase + k0;
        const __hip_bfloat16* Bb = Bbase + k0;
        unsigned short* sAb = sMem + buf * BUFS;
        unsigned short* sBb = sAb + 4096;
#pragma unroll
        for (int jj = 0; jj < 2; jj++) {
            int idx = jj * 256 + tid;
            int r = idx >> 2, c = (idx & 3) * 8;
            __builtin_amdgcn_global_load_lds(
                (const __attribute__((address_space(1))) void*)(Ab + (size_t)r * lda + c),
                (__attribute__((address_space(3))) void*)(sAb + (jj * 256 + wave * 64) * 8),
                16, 0, 0);
        }
#pragma unroll
        for (int jj = 0; jj < 2 * NTILES; jj++) {
            int idx = jj * 256 + tid;
            int r = idx >> 2, c = (idx & 3) * 8;
            __builtin_amdgcn_global_load_lds(
                (const __attribute__((address_space(1))) void*)(Bb + (size_t)r * ldb + c),
                (__attribute__((address_space(3))) void*)(sBb + (jj * 256 + wave * 64) * 8),
                16, 0, 0);
        }
    };

    f32x4 acc[NTILES][4][4];
#pragma unroll
    for (int ct = 0; ct < NTILES; ct++)
        for (int i = 0; i < 4; i++)
            for (int j2 = 0; j2 < 4; j2++) acc[ct][i][j2] = (f32x4){0.f, 0.f, 0.f, 0.f};

    stage(0, 0);
    __syncthreads();                       // drains tile-0 DMA, syncs all waves
    int cur = 0;
    for (int k0 = 0; k0 < K; k0 += 32) {
        if (k0 + 32 < K) stage(cur ^ 1, k0 + 32);      // next tile in flight
        const unsigned short* sAc = sMem + cur * BUFS;
        const unsigned short* sBc = sAc + 4096;
        bf16x8 af[4];
#pragma unroll
        for (int i = 0; i < 4; i++)
            af[i] = *(const bf16x8*)(&sAc[(wr * 64 + i * 16 + ln) * 32 + q * 8]);
#pragma unroll
        for (int ct = 0; ct < NTILES; ct++) {
            bf16x8 bf[4];
#pragma unroll
            for (int j2 = 0; j2 < 4; j2++)
                bf[j2] = *(const bf16x8*)(&sBc[(ct * 128 + wc * 64 + j2 * 16 + ln) * 32 + q * 8]);
#pragma unroll
            for (int i = 0; i < 4; i++)
#pragma unroll
                for (int j2 = 0; j2 < 4; j2++)
                    acc[ct][i][j2] = __builtin_amdgcn_mfma_f32_16x16x32_bf16(af[i], bf[j2], acc[ct][i][j2], 0, 0, 0);
        }
        __syncthreads();                   // drains next-tile DMA + readers done
        cur ^= 1;
    }

    if constexpr (OUT_BF16) {
#pragma unroll
        for (int ct = 0; ct < NTILES; ct++) {
            if (ct) __syncthreads();       // prev store pass LDS reads done
            // phase 1: values -> sMem C-tile [128][CTS]
            for (int j2 = 0; j2 < 4; j2++) {
                int cl  = wc * 64 + j2 * 16 + ln;
                int col = nt * (128 * NTILES) + ct * 128 + cl;
                float bv = bias ? bf2f(bias[col]) : 0.f;
                float ls = 0.f, ls2 = 0.f;
                for (int i = 0; i < 4; i++) {
                    for (int r = 0; r < 4; r++) {
                        int rl = wr * 64 + i * 16 + q * 4 + r;
                        float v = acc[ct][i][j2][r] + bv;
                        if (st && mt * 128 + rl < M) { ls += v; ls2 += v * v; }
                        if (act == 1) v = softplus_f(v);
                        sMem[rl * CTS + cl] = f2bfbits(v);
                    }
                }
                if (st) { atomicAdd(&sS[ct * 128 + cl], ls); atomicAdd(&sS2[ct * 128 + cl], ls2); }
            }
            __syncthreads();
            // phase 2: coalesced stores — 16 lanes = one 256B row run.
#pragma unroll
            for (int it = 0; it < 8; it++) {
                int fi = it * 256 + tid;
                int rl = fi >> 4, c8 = (fi & 15) * 8;
                int row = mt * 128 + rl;
                if (row < M) {
                    uint4 v = *(const uint4*)(&sMem[rl * CTS + c8]);
                    *(uint4*)((__hip_bfloat16*)Cp + (size_t)row * ldc +
                              nt * (128 * NTILES) + ct * 128 + c8) = v;
                }
            }
        }
        if (st) {
            for (int i = tid; i < 128 * NTILES; i += 256) {
                int col = nt * (128 * NTILES) + i;
                atomicAdd(&st[col], sS[i]);
                atomicAdd(&st[AF + col], sS2[i]);
            }
        }
    } else {
        for (int ct = 0; ct < NTILES; ct++) {
            for (int j2 = 0; j2 < 4; j2++) {
                int cl  = wc * 64 + j2 * 16 + ln;
                int col = nt * (128 * NTILES) + ct * 128 + cl;
                float bv = bias ? bf2f(bias[col]) : 0.f;
                for (int i = 0; i < 4; i++) {
                    for (int r = 0; r < 4; r++) {
                        int row = mt * 128 + wr * 64 + i * 16 + q * 4 + r;
                        if (row >= M) continue;
                        float v = acc[ct][i][j2][r] + bv;
                        if (act == 1) v = softplus_f(v);
                        ((float*)Cp)[(size_t)row * ldc + col] = v;
                    }
                }
            }
        }
    }
}

// ---------------- fused conv v11 --------------------------------------------
// 4 atoms/block, 5000 blocks. Per phase (256 cols): issue bfr (both halves)
// FIRST, then yy/xau/b1u gathers -> MFMA (waits only on bfr, gathers stay in
// flight) -> z to LDS -> barrier -> epilogue consumes gather regs.
// Neighbor idx lives in sNF's per-row pad (elem 64) -> LDS fits 5 blocks/CU.
__global__ __launch_bounds__(256)
void conv_fused(const void* __restrict__ nf,              // [N][12][64]
                const unsigned* __restrict__ dflag,
                int prepped,                              // 1: nf canonical bf16
                const int* __restrict__ nidx,             // [N][12]
                const __hip_bfloat16* __restrict__ xay,   // [N][1024]: xa | y
                const __hip_bfloat16* __restrict__ b1l,   // [512]
                const __hip_bfloat16* __restrict__ w1TfL, // [512][64]
                __hip_bfloat16* __restrict__ ns)          // [N][512]
{
    __shared__ __align__(16) unsigned short sNF[48 * 72];   // 6.9 KB (pad holds idx)
    __shared__ __align__(16) unsigned short sZ[48 * ZS2];   // 25.7 KB
    // total 32640 B -> 32768 alloc -> 5 blocks/CU

    int tid = threadIdx.x;
    int ab  = blockIdx.x * 4;

    if (prepped || dflag[0] == 0u) {
        const __hip_bfloat16* nfB = (const __hip_bfloat16*)nf;
        for (int i = tid; i < 48 * 8; i += 256) {
            int r = i >> 3, ch = i & 7;
            uint4 v = *(const uint4*)(nfB + (size_t)(ab * 12 + r) * 64 + ch * 8);
            *(uint4*)(&sNF[r * 72 + ch * 8]) = v;
        }
    } else {
        const float* nfF = (const float*)nf;
        for (int i = tid; i < 48 * 8; i += 256) {
            int r = i >> 3, ch = i & 7;
            const float* src = nfF + (size_t)(ab * 12 + r) * 64 + ch * 8;
            float4 v0 = *(const float4*)(src);
            float4 v1 = *(const float4*)(src + 4);
            unsigned short* d = &sNF[r * 72 + ch * 8];
            d[0] = f2bfbits(v0.x); d[1] = f2bfbits(v0.y);
            d[2] = f2bfbits(v0.z); d[3] = f2bfbits(v0.w);
            d[4] = f2bfbits(v1.x); d[5] = f2bfbits(v1.y);
            d[6] = f2bfbits(v1.z); d[7] = f2bfbits(v1.w);
        }
    }
    // neighbor idx into sNF row pad (elem 64; staging writes only elems 0..63;
    // byte offset (r*72+64)*2 = 144r+128 is 4B-aligned)
    if (tid < 48) *(int*)&sNF[tid * 72 + 64] = nidx[ab * 12 + tid];
    __syncthreads();

    int wave = tid >> 6, lane = tid & 63, q = lane >> 4, ln = lane & 15;
    int c0 = wave * 32;                    // MFMA: wave covers 32 cols of each tile
    int a = wave, half = lane >> 5, lc = lane & 31;  // epilogue mapping
    int n = ab + a;
    int zc = half * 128 + lc * 4;          // col within tile-pair

    for (int tp = 0; tp < 2; tp++) {
        if (tp) __syncthreads();           // prev epilogue done reading sZ
        int gc = tp * 256 + zc;

        // ---- vmem issue order matters: bfr FIRST (MFMA waits only on these,
        // vmcnt(14) leaves the gathers in flight), then the slow gathers.
        bf16x8 bfr[2][2][2];               // [t2][c2][ks]
#pragma unroll
        for (int t2 = 0; t2 < 2; t2++) {
            int cb = (tp * 2 + t2) * 128;
#pragma unroll
            for (int c2 = 0; c2 < 2; c2++)
#pragma unroll
                for (int ks = 0; ks < 2; ks++)
                    bfr[t2][c2][ks] = *(const bf16x8*)(w1TfL +
                        (size_t)(cb + c0 + c2 * 16 + ln) * 64 + ks * 32 + q * 8);
        }
        uint2 yy[12];
#pragma unroll
        for (int m = 0; m < 12; m++) {
            int gi = *(const int*)&sNF[(a * 12 + m) * 72 + 64];
            yy[m] = *(const uint2*)((const char*)xay +
                                    ((size_t)(unsigned)gi << 11) + 1024u + gc * 2);
        }
        uint2 xau = *(const uint2*)(xay + (size_t)n * 1024 + gc);
        uint2 b1u = *(const uint2*)(b1l + gc);

#pragma unroll
        for (int t2 = 0; t2 < 2; t2++) {
            f32x4 acc[3][2];
            for (int rt = 0; rt < 3; rt++)
                for (int c2 = 0; c2 < 2; c2++) acc[rt][c2] = (f32x4){0.f, 0.f, 0.f, 0.f};
            for (int rt = 0; rt < 3; rt++) {
                bf16x8 a0 = *(const bf16x8*)(&sNF[(rt * 16 + ln) * 72 + q * 8]);
                bf16x8 a1 = *(const bf16x8*)(&sNF[(rt * 16 + ln) * 72 + 32 + q * 8]);
                acc[rt][0] = __builtin_amdgcn_mfma_f32_16x16x32_bf16(a0, bfr[t2][0][0], acc[rt][0], 0, 0, 0);
                acc[rt][0] = __builtin_amdgcn_mfma_f32_16x16x32_bf16(a1, bfr[t2][0][1], acc[rt][0], 0, 0, 0);
                acc[rt][1] = __builtin_amdgcn_mfma_f32_16x16x32_bf16(a0, bfr[t2][1][0], acc[rt][1], 0, 0, 0);
                acc[rt][1] = __builtin_amdgcn_mfma_f32_16x16x32_bf16(a1, bfr[t2][1][1], acc[rt][1], 0, 0, 0);
            }
            for (int rt = 0; rt < 3; rt++)
                for (int c2 = 0; c2 < 2; c2++)
                    for (int r = 0; r < 4; r++)
                        sZ[(rt * 16 + q * 4 + r) * ZS2 + t2 * 128 + c0 + c2 * 16 + ln] =
                            f2bfbits(acc[rt][c2][r]);
        }
        __syncthreads();

        // epilogue: thread owns (atom=wave, 4 cols), loop m
        float xa0 = bfbits2f((unsigned short)(xau.x & 0xffff)) +
                    bfbits2f((unsigned short)(b1u.x & 0xffff));
        float xa1 = bfbits2f((unsigned short)(xau.x >> 16)) +
                    bfbits2f((unsigned short)(b1u.x >> 16));
        float xa2 = bfbits2f((unsigned short)(xau.y & 0xffff)) +
                    bfbits2f((unsigned short)(b1u.y & 0xffff));
        float xa3 = bfbits2f((unsigned short)(xau.y >> 16)) +
                    bfbits2f((unsigned short)(b1u.y >> 16));
        float r0 = 0.f, r1 = 0.f, r2 = 0.f, r3 = 0.f;
#pragma unroll
        for (int m = 0; m < 12; m++) {
            uint2 zz = *(const uint2*)(&sZ[(a * 12 + m) * ZS2 + zc]);
            float v0 = bfbits2f((unsigned short)(zz.x & 0xffff)) + xa0 +
                       bfbits2f((unsigned short)(yy[m].x & 0xffff));
            float v1 = bfbits2f((unsigned short)(zz.x >> 16)) + xa1 +
                       bfbits2f((unsigned short)(yy[m].x >> 16));
            float v2 = bfbits2f((unsigned short)(zz.y & 0xffff)) + xa2 +
                       bfbits2f((unsigned short)(yy[m].y & 0xffff));
            float v3 = bfbits2f((unsigned short)(zz.y >> 16)) + xa3 +
                       bfbits2f((unsigned short)(yy[m].y >> 16));
            if (m < 6) {
                v0 = fmaxf(v0, 0.f); v1 = fmaxf(v1, 0.f);
                v2 = fmaxf(v2, 0.f); v3 = fmaxf(v3, 0.f);
            } else {
                v0 = softplus_f(v0); v1 = softplus_f(v1);
                v2 = softplus_f(v2); v3 = softplus_f(v3);
            }
            r0 += v0; r1 += v1; r2 += v2; r3 += v3;
        }
        uint2 o;
        o.x = (unsigned)f2bfbits(r0) | ((unsigned)f2bfbits(r1) << 16);
        o.y = (unsigned)f2bfbits(r2) | ((unsigned)f2bfbits(r3) << 16);
        *(uint2*)(ns + (size_t)n * F2 + gc) = o;
    }
}

// ---------------- batchnorm apply (stats fused into h2 GEMM) -----------------
__global__ __launch_bounds__(256)
void bn_apply(const __hip_bfloat16* __restrict__ h2, const float* __restrict__ st,
              const __hip_bfloat16* __restrict__ x,
              const __hip_bfloat16* __restrict__ gamma,
              const __hip_bfloat16* __restrict__ beta,
              __hip_bfloat16* __restrict__ xo) {
    int i = (blockIdx.x * 256 + threadIdx.x) * 8;
    int c = i & 255;
    uint4 hv = *(const uint4*)(h2 + i);
    uint4 xv = *(const uint4*)(x + i);
    unsigned hw[4] = {hv.x, hv.y, hv.z, hv.w};
    unsigned xw[4] = {xv.x, xv.y, xv.z, xv.w};
    unsigned ow[4];
    float r[8];
#pragma unroll
    for (int k = 0; k < 8; k++) {
        int cc = c + k;
        float mu  = st[cc] * (1.f / 20000.f);
        float var = fmaxf(st[AF + cc] * (1.f / 20000.f) - mu * mu, 0.f);
        unsigned hh = hw[k >> 1], xx = xw[k >> 1];
        float h  = bfbits2f((unsigned short)((k & 1) ? (hh >> 16) : (hh & 0xffff)));
        float xf = bfbits2f((unsigned short)((k & 1) ? (xx >> 16) : (xx & 0xffff)));
        float t = (h - mu) * rsqrtf(var + BN_EPS) * bf2f(gamma[cc]) + bf2f(beta[cc]);
        r[k] = softplus_f(xf + t);
    }
#pragma unroll
    for (int k = 0; k < 4; k++)
        ow[k] = pack2bf(r[2 * k], r[2 * k + 1]);
    *(uint4*)(xo + i) = make_uint4(ow[0], ow[1], ow[2], ow[3]);
}

// ---------------- readout: segment mean + 2-layer MLP ------------------------
__global__ __launch_bounds__(256)
void readout(const __hip_bfloat16* __restrict__ x, const int* __restrict__ m1,
             const __hip_bfloat16* __restrict__ smalls,
             const unsigned* __restrict__ dflag,
             void* __restrict__ outp) {
    __shared__ float sc[AF + 4];
    __shared__ float sred[4];
    bool isf32 = dflag[0] != 0u;
    int b = blockIdx.x, tid = threadIdx.x;
    float s = 0.f;
    for (int j = 0; j < KK; j++) {
        int row = m1[b * KK + j];
        s += bf2f(x[(size_t)row * AF + tid]);
    }
    sc[tid] = softplus_f(s * (1.f / (float)KK));
    if (tid < 4) sc[AF + tid] = softplus_f(bf2f(smalls[OFF_M2 + b * 4 + tid]));
    __syncthreads();
    float acc = bf2f(smalls[OFF_FCB + tid]);
    for (int k = 0; k < AF + 4; k++) acc += sc[k] * bf2f(smalls[OFF_FCW + k * 256 + tid]);
    float h = softplus_f(acc);
    float v = h * bf2f(smalls[OFF_OW + tid]);
    for (int off = 32; off > 0; off >>= 1) v += __shfl_down(v, off);
    if ((tid & 63) == 0) sred[tid >> 6] = v;
    __syncthreads();
    if (tid == 0) {
        float o = sred[0] + sred[1] + sred[2] + sred[3] + bf2f(smalls[OFF_OB]);
        if (isf32) ((float*)outp)[b] = o;
        else       ((__hip_bfloat16*)outp)[b] = f2bf(o);
    }
}

// ---------------- host ------------------------------------------------------
extern "C" void kernel_launch(void* const* d_in, const int* in_sizes, int n_in,
                              void* d_out, int out_size, void* d_ws, size_t ws_size,
                              hipStream_t stream) {
    const void* atom_fea = d_in[0];
    const void* nbr_fea  = d_in[1];
    const int*  nbr_idx  = (const int*)d_in[2];
    const int*  m1_idx   = (const int*)d_in[3];
    /* d_in[4] seg_ids: unused */
    const void* m2_fea = d_in[5];
    const void* emb_w  = d_in[6];
    const void* emb_b  = d_in[7];
    const void* w1     = d_in[8];
    const void* b1     = d_in[9];
    const void* w2     = d_in[10];
    const void* b2     = d_in[11];
    const void* gamma  = d_in[12];
    const void* beta   = d_in[13];
    const void* fc_w   = d_in[14];
    const void* fc_b   = d_in[15];
    const void* out_w  = d_in[16];
    const void* out_b  = d_in[17];

    // ---- aliased workspace (~86 MB core + 30.7 MB optional nfb) ----
    char* ws = (char*)d_ws;
    size_t off = 0;
    auto alloc = [&](size_t bytes) -> char* {
        char* p = ws + off;
        off += (bytes + 255) & ~(size_t)255;
        return p;
    };
    __hip_bfloat16* w1T2   = (__hip_bfloat16*)alloc((size_t)S_W12 * 2);
    __hip_bfloat16* w1Tf   = (__hip_bfloat16*)alloc((size_t)S_W1F * 2);
    __hip_bfloat16* w2T    = (__hip_bfloat16*)alloc((size_t)S_W2 * 2);
    __hip_bfloat16* smalls = (__hip_bfloat16*)alloc((size_t)N_SMALL * 2);
    __hip_bfloat16* xb0    = (__hip_bfloat16*)alloc((size_t)N_PAD * AF * 2);   // padded rows
    __hip_bfloat16* xb1    = (__hip_bfloat16*)alloc((size_t)N_PAD * AF * 2);   // padded rows
    char*           regXY  = alloc((size_t)N_ATOM * 1024 * 2);
    char*           regZ   = alloc((size_t)N_PAD * F2 * 2);                    // padded rows
    float*          stats  = (float*)alloc((size_t)3 * 2 * AF * 4);
    unsigned*       dflag  = (unsigned*)alloc(256);
    char*           nfb    = alloc((size_t)N_ATOM * 12 * 64 * 2);   // 30.72 MB
    int use_nfb = (ws_size >= off) ? 1 : 0;

    __hip_bfloat16* xay    = (__hip_bfloat16*)regXY;
    __hip_bfloat16* h2     = (__hip_bfloat16*)regXY;
    __hip_bfloat16* af_pad = (__hip_bfloat16*)(regXY + (size_t)N_ATOM * F2 * 2);  // 20.48MB free half
    __hip_bfloat16* embT   = (__hip_bfloat16*)regZ;
    __hip_bfloat16* nsb    = (__hip_bfloat16*)regZ;

    detect_dtype<<<1, 1, 0, stream>>>((const unsigned*)gamma, dflag);
    (void)hipMemsetAsync(stats, 0, (size_t)3 * 2 * AF * 4, stream);

    if (use_nfb)
        prep_nf<<<(N_ATOM * 12 * 64 / 4 + 255) / 256, 256, 0, stream>>>(nbr_fea, dflag,
                                                                        (unsigned*)nfb);
    prep_all<<<(S_TOT + 255) / 256, 256, 0, stream>>>(
        atom_fea, emb_w, w1, w2, b1, b2, gamma, beta, emb_b, fc_b, fc_w,
        out_w, out_b, m2_fea, dflag, af_pad, embT, w1T2, w1Tf, w2T, smalls);

    const int MT = (N_ATOM + 127) / 128;   // 157 row-tiles

    // embed: x = softplus(af_pad @ emb_w + emb_b)  (314 blocks, ntB=2)
    gemm_kernel<true, 1><<<MT * 2, 256, 0, stream>>>(af_pad, ORIG_P, embT, ORIG_P,
                                                     xb0, N_ATOM, AF, ORIG_P,
                                                     smalls + OFF_EMBB, 1, nullptr, 2);

    const void* nf_conv = use_nfb ? (const void*)nfb : nbr_fea;

    __hip_bfloat16* xc = xb0;
    __hip_bfloat16* xn = xb1;
    for (int l = 0; l < 3; l++) {
        // xy: 1256 blocks, ntB=8 — XCD swizzle keeps each A-tile on one XCD
        gemm_kernel<true, 1><<<MT * 8, 256, 0, stream>>>(xc, AF, w1T2 + (size_t)l * 1024 * 256, 256,
                                                         xay, N_ATOM, 1024, AF, nullptr, 0, nullptr, 8);
        conv_fused<<<N_ATOM / 4, 256, 0, stream>>>(nf_conv, dflag, use_nfb, nbr_idx, xay,
                                                   smalls + OFF_B1 + l * F2,
                                                   w1Tf + (size_t)l * 512 * 64, nsb);
        float* stl = stats + l * 2 * AF;
        gemm_kernel<true, 1><<<MT * 2, 256, 0, stream>>>(nsb, F2, w2T + (size_t)l * AF * F2, F2,
                                                         h2, N_ATOM, AF, F2,
                                                         smalls + OFF_B2 + l * AF, 0, stl, 2);
        bn_apply<<<(N_ATOM * AF / 8) / 256, 256, 0, stream>>>(h2, stl, xc,
                                                              smalls + OFF_GAM + l * AF,
                                                              smalls + OFF_BET + l * AF, xn);
        __hip_bfloat16* t = xc; xc = xn; xn = t;
    }
    readout<<<BB, 256, 0, stream>>>(xc, m1_idx, smalls, dflag, d_out);
}